// Round 9
// baseline (288.615 us; speedup 1.0000x reference)
//
#include <hip/hip_runtime.h>
#include <hip/hip_bf16.h>
#include <cstdint>
#include <cstddef>

#define B_ 4
#define S_ 2048
#define E_ 1024
#define H_ 16
#define BS_ (B_*S_)
#define BHS_ (B_*H_*S_)
#define MAXCAND (1u<<18)
#define MAXSURV 8192
#define SLOTS 512

static constexpr float T_SEARCH = 50.0f;  // bf16 search threshold (~4.5-sigma over cut)
static constexpr float T_CUT    = 48.5f;  // exact fp32 cut; e^-48.5 contribution ~300x under tol

typedef __attribute__((ext_vector_type(8))) short bf16x8;
typedef __attribute__((ext_vector_type(4))) float f32x4;

static __device__ __forceinline__ unsigned short f32_to_bf16(float f){
  unsigned u = __float_as_uint(f);
  return (unsigned short)((u + 0x7fffu + ((u >> 16) & 1u)) >> 16);  // RNE
}
static __device__ __forceinline__ void gload_lds16(const void* g, void* l){
  __builtin_amdgcn_global_load_lds(
      (const __attribute__((address_space(1))) unsigned int*)g,
      (__attribute__((address_space(3))) unsigned int*)l, 16, 0, 0);
}
static __device__ __forceinline__ float dot4(float4 a, float4 b){
  return a.x*b.x + a.y*b.y + a.z*b.z + a.w*b.w;
}

// ------- fused: f32->bf16 casts (x, Wq, Wk) + per-batch mask compaction -------
__global__ void cast_compact_k(const float* __restrict__ x,
                               const float* __restrict__ wq, const float* __restrict__ wk,
                               const int* __restrict__ mask,
                               unsigned short* __restrict__ xb, unsigned short* __restrict__ wqkb,
                               int* __restrict__ tmap, int* __restrict__ vcount){
  int blk = blockIdx.x;
  if (blk >= 5120){                     // mask compaction, b = blk-5120
    int b = blk - 5120, tid = threadIdx.x;
    __shared__ int ps[256];
    int loc[8]; int cnt = 0;
    #pragma unroll
    for (int j = 0; j < 8; ++j){ int m = mask[b*S_ + tid*8 + j]; loc[j] = m; cnt += m; }
    ps[tid] = cnt; __syncthreads();
    for (int off = 1; off < 256; off <<= 1){
      int v = (tid >= off) ? ps[tid-off] : 0;
      __syncthreads(); ps[tid] += v; __syncthreads();
    }
    int base = ps[tid] - cnt;
    #pragma unroll
    for (int j = 0; j < 8; ++j)
      if (loc[j]){ tmap[b*S_ + base] = tid*8 + j; ++base; }
    if (tid == 255) vcount[b] = ps[255];
    return;
  }
  const float* src; unsigned short* dst; int base;
  if (blk < 4096){ src = x;  dst = xb;                  base = blk; }
  else if (blk < 4608){ src = wq; dst = wqkb;           base = blk - 4096; }
  else { src = wk; dst = wqkb + (size_t)E_*E_;          base = blk - 4608; }
  size_t i = (size_t)base*256 + threadIdx.x;            // 8 elems per item
  const float4* s4 = reinterpret_cast<const float4*>(src) + 2*i;
  float4 a = s4[0], b = s4[1];
  float v[8] = {a.x,a.y,a.z,a.w,b.x,b.y,b.z,b.w};
  union { unsigned short us[8]; uint4 u4; } o;
  #pragma unroll
  for (int j = 0; j < 8; ++j) o.us[j] = f32_to_bf16(v[j]);
  reinterpret_cast<uint4*>(dst)[i] = o.u4;
}

// ------- fused Q|K projection, head-major out, norms in epilogue -------
__global__ __launch_bounds__(256) void proj_hm_k(
    const unsigned short* __restrict__ xb,
    const unsigned short* __restrict__ Wqkb,
    const int* __restrict__ tmap, const int* __restrict__ vcount,
    unsigned short* __restrict__ Qhm, unsigned short* __restrict__ Kc,
    float* __restrict__ qn, float* __restrict__ knc){
  const int z = blockIdx.z;
  const int m0 = blockIdx.x * 128, n0 = blockIdx.y * 128;
  const int bb = m0 >> 11, tc0 = m0 & 2047;
  const int vc = vcount[bb];
  if (z == 1 && tc0 >= vc) return;
  const unsigned short* Bw = Wqkb + (size_t)z*E_*E_;
  unsigned short* Out = z ? Kc : Qhm;
  float* Nrm = z ? knc : qn;

  __shared__ unsigned short At[128*64];
  __shared__ unsigned short Bt[128*64];
  const int tid = threadIdx.x, wave = tid >> 6, lane = tid & 63;
  const int wr = wave >> 1, wc = wave & 1;
  const int fr = lane & 15, fc = lane >> 4;
  const int srow = lane >> 3, sc = lane & 7;

  int arow[4];
  #pragma unroll
  for (int i = 0; i < 4; ++i){
    int r = wave*32 + i*8 + srow;
    int tc = tc0 + r;
    arow[i] = z ? ((tc < vc) ? tmap[bb*S_ + tc] : 0) : tc;
  }

  f32x4 acc[4][4] = {};

  for (int k0 = 0; k0 < 1024; k0 += 64){
    #pragma unroll
    for (int i = 0; i < 4; ++i){
      int r  = wave*32 + i*8 + srow;
      int cs = sc ^ (r & 7);
      gload_lds16(xb + ((size_t)(bb << 11) + arow[i])*1024 + k0 + cs*8, &At[(wave*32 + i*8)*64]);
      gload_lds16(Bw + (size_t)(n0 + r)*1024 + k0 + cs*8, &Bt[(wave*32 + i*8)*64]);
    }
    __syncthreads();
    #pragma unroll
    for (int kk = 0; kk < 2; ++kk){
      bf16x8 af[4], bf_[4];
      #pragma unroll
      for (int mf = 0; mf < 4; ++mf){
        int r = wr*64 + mf*16 + fr;
        af[mf] = *reinterpret_cast<const bf16x8*>(&At[r*64 + ((kk*4 + fc) ^ (r & 7))*8]);
      }
      #pragma unroll
      for (int nf = 0; nf < 4; ++nf){
        int r = wc*64 + nf*16 + fr;
        bf_[nf] = *reinterpret_cast<const bf16x8*>(&Bt[r*64 + ((kk*4 + fc) ^ (r & 7))*8]);
      }
      #pragma unroll
      for (int mf = 0; mf < 4; ++mf)
        #pragma unroll
        for (int nf = 0; nf < 4; ++nf)
          acc[mf][nf] = __builtin_amdgcn_mfma_f32_16x16x32_bf16(af[mf], bf_[nf], acc[mf][nf], 0, 0, 0);
    }
    __syncthreads();
  }

  const int h = (n0 >> 6) + wc;
  const size_t rowbase = (size_t)((bb << 4) | h)*S_;
  #pragma unroll
  for (int mf = 0; mf < 4; ++mf)
    #pragma unroll
    for (int r = 0; r < 4; ++r){
      int rowb = tc0 + wr*64 + mf*16 + fc*4 + r;
      #pragma unroll
      for (int nf = 0; nf < 4; ++nf)
        Out[(rowbase + rowb)*64 + nf*16 + fr] = f32_to_bf16(acc[mf][nf][r]);
      float s = 0.f;
      #pragma unroll
      for (int nf = 0; nf < 4; ++nf) s += acc[mf][nf][r]*acc[mf][nf][r];
      s += __shfl_xor(s, 1); s += __shfl_xor(s, 2);
      s += __shfl_xor(s, 4); s += __shfl_xor(s, 8);
      if (fr == 0) Nrm[rowbase + rowb] = s;
    }
}

// ------- register-resident candidate search: tiny test loop + cold emit pass -------
#define SRCH_LOADB(B_ARR, KN_ARR, c_) do{                                      \
  int t0_ = (c_)*64;                                                           \
  _Pragma("unroll") for (int nf_ = 0; nf_ < 4; ++nf_){                         \
    _Pragma("unroll") for (int kk_ = 0; kk_ < 2; ++kk_)                        \
      B_ARR[nf_][kk_] = *reinterpret_cast<const bf16x8*>(                      \
          Kh + (size_t)(t0_ + nf_*16 + fr)*64 + (kk_*4 + fc)*8);               \
    int t_ = t0_ + nf_*16 + fr;                                                \
    float kv_ = knb[t_];                                                       \
    KN_ARR[nf_] = (t_ < vc) ? 0.5f*kv_ : 1e30f;                                \
  }                                                                            \
}while(0)

#define SRCH_MFMA(B_ARR, ACC_) do{                                             \
  _Pragma("unroll") for (int mf_ = 0; mf_ < 2; ++mf_)                          \
  _Pragma("unroll") for (int nf_ = 0; nf_ < 4; ++nf_){                         \
    ACC_[mf_][nf_] = __builtin_amdgcn_mfma_f32_16x16x32_bf16(                  \
        af[mf_][0], B_ARR[nf_][0], z4, 0, 0, 0);                               \
    ACC_[mf_][nf_] = __builtin_amdgcn_mfma_f32_16x16x32_bf16(                  \
        af[mf_][1], B_ARR[nf_][1], ACC_[mf_][nf_], 0, 0, 0);                   \
  }                                                                            \
}while(0)

// hot-path test: no atomics, no stores, one scalar bit per chunk
#define SRCH_TEST(B_ARR, KN_ARR, c_) do{                                       \
  f32x4 acc[2][4];                                                             \
  SRCH_MFMA(B_ARR, acc);                                                       \
  f32x4 m4 = acc[0][0];                                                        \
  _Pragma("unroll") for (int mf_ = 0; mf_ < 2; ++mf_)                          \
  _Pragma("unroll") for (int nf_ = 0; nf_ < 4; ++nf_)                          \
    if (mf_ || nf_){                                                           \
      _Pragma("unroll") for (int r_ = 0; r_ < 4; ++r_)                         \
        m4[r_] = fmaxf(m4[r_], acc[mf_][nf_][r_]);                             \
    }                                                                          \
  float mx = fmaxf(fmaxf(m4[0], m4[1]), fmaxf(m4[2], m4[3]));                  \
  float knmin = fminf(fminf(KN_ARR[0], KN_ARR[1]),                             \
                      fminf(KN_ARR[2], KN_ARR[3]));                            \
  if (__any(mx > qamin + knmin)) hitmask |= (1u << (c_));                      \
}while(0)

// cold-path emit: full scan of a known-hit chunk
#define SRCH_EMIT(B_ARR, KN_ARR, c_) do{                                       \
  int t0_ = (c_)*64;                                                           \
  f32x4 acc[2][4];                                                             \
  SRCH_MFMA(B_ARR, acc);                                                       \
  _Pragma("unroll") for (int mf_ = 0; mf_ < 2; ++mf_)                          \
  _Pragma("unroll") for (int nf_ = 0; nf_ < 4; ++nf_)                          \
  _Pragma("unroll") for (int r_ = 0; r_ < 4; ++r_){                            \
    if (acc[mf_][nf_][r_] > qa[mf_*4+r_] + KN_ARR[nf_]){                       \
      int t_ = t0_ + nf_*16 + fr;                                              \
      if (t_ < vc){                                                            \
        int s_ = s0 + mf_*16 + fc*4 + r_;                                      \
        unsigned idx_ = atomicAdd(cnt, 1u);                                    \
        if (idx_ < MAXCAND)                                                    \
          cand[idx_] = ((unsigned)b << 26) | ((unsigned)h << 22)               \
                     | ((unsigned)s_ << 11) | (unsigned)t_;                    \
        qflag[(bh << 11) | s_] = 1;                                            \
        kflag[(bh << 11) | t_] = 1;                                            \
      }                                                                        \
    }                                                                          \
  }                                                                            \
}while(0)

__global__ __launch_bounds__(256) void search_k(
    const unsigned short* __restrict__ Qhm, const unsigned short* __restrict__ Kc,
    const float* __restrict__ qn, const float* __restrict__ knc,
    const int* __restrict__ vcount,
    unsigned* __restrict__ cnt, unsigned* __restrict__ cand,
    int* __restrict__ qflag, int* __restrict__ kflag){
  const int wave = threadIdx.x >> 6, lane = threadIdx.x & 63;
  const int bh = blockIdx.x & 63;
  const int s0 = ((blockIdx.x >> 6)*4 + wave)*32;  // 64 strips of 32 rows
  const int b = bh >> 4, h = bh & 15;
  const int vc = vcount[b];
  const int nt = (vc + 63) >> 6;                   // <= 32
  if (nt == 0) return;
  const int fr = lane & 15, fc = lane >> 4;
  const unsigned short* Qh = Qhm + (size_t)bh*S_*64;
  const unsigned short* Kh = Kc + (size_t)bh*S_*64;
  const float* qnb = qn + (size_t)bh*S_;
  const float* knb = knc + (size_t)bh*S_;
  const f32x4 z4 = {0.f, 0.f, 0.f, 0.f};

  bf16x8 af[2][2];
  #pragma unroll
  for (int mf = 0; mf < 2; ++mf)
    #pragma unroll
    for (int kk = 0; kk < 2; ++kk)
      af[mf][kk] = *reinterpret_cast<const bf16x8*>(
          Qh + (size_t)(s0 + mf*16 + fr)*64 + (kk*4 + fc)*8);

  float qa[8];
  #pragma unroll
  for (int mf = 0; mf < 2; ++mf)
    #pragma unroll
    for (int r = 0; r < 4; ++r)
      qa[mf*4+r] = 0.5f*(qnb[s0 + mf*16 + fc*4 + r] - T_SEARCH);
  float qamin = qa[0];
  #pragma unroll
  for (int j = 1; j < 8; ++j) qamin = fminf(qamin, qa[j]);

  unsigned hitmask = 0u;
  bf16x8 b0[4][2], b1[4][2];
  float kn0[4], kn1[4];

  // ---- phase A: tiny test-only loop (2-deep ping-pong) ----
  SRCH_LOADB(b0, kn0, 0);
  for (int c = 0; c < nt; c += 2){
    if (c + 1 < nt) SRCH_LOADB(b1, kn1, c+1);
    SRCH_TEST(b0, kn0, c);
    if (c + 1 >= nt) break;
    if (c + 2 < nt) SRCH_LOADB(b0, kn0, c+2);
    SRCH_TEST(b1, kn1, c+1);
  }

  // ---- phase B: cold emit pass over hit chunks (wave-uniform mask) ----
  while (hitmask){
    int c = __builtin_ctz(hitmask);
    hitmask &= hitmask - 1u;
    SRCH_LOADB(b0, kn0, c);
    SRCH_EMIT(b0, kn0, c);
  }
}

// ---------------- build per-head row lists + slot maps ----------------
__global__ void rowlist_k(const int* __restrict__ qflag, const int* __restrict__ kflag,
                          int* __restrict__ lcnt,
                          int* __restrict__ qlist, int* __restrict__ klist,
                          int* __restrict__ qslotm, int* __restrict__ kslotm){
  int side = blockIdx.y;
  int i = blockIdx.x*256 + threadIdx.x;
  const int* flag = side ? kflag : qflag;
  if (!flag[i]) return;
  int h = (i >> 11) & 15, b = i >> 15, row = i & 2047;
  int slot = atomicAdd(&lcnt[side*16 + h], 1);
  int* list = side ? klist : qlist;
  int* sm   = side ? kslotm : qslotm;
  if (slot < SLOTS){ list[h*SLOTS + slot] = (b << 11) | row; sm[i] = slot; }
  else sm[i] = -1;
}

// ---------------- exact fp32 rows, head-grouped, E-part-split ----------------
__global__ __launch_bounds__(256) void exact_rows_k(
    const float* __restrict__ x, const int* __restrict__ tmap,
    const float* __restrict__ Wq, const float* __restrict__ Wk,
    const float* __restrict__ Wv,
    const int* __restrict__ lcnt,
    const int* __restrict__ qlist, const int* __restrict__ klist,
    float* __restrict__ qex, float* __restrict__ kex, float* __restrict__ vex){
  int p = blockIdx.x, h = blockIdx.y, z = blockIdx.z;
  int R = lcnt[(z == 0 ? 0 : 16) + h]; if (R > SLOTS) R = SLOTS;
  if (R == 0) return;
  const float* W = (z == 0) ? Wq : (z == 1 ? Wk : Wv);
  const int* list = (z == 0) ? qlist : klist;
  float* dst = (z == 0) ? qex : (z == 1 ? kex : vex);
  int d = threadIdx.x >> 2, j = threadIdx.x & 3;
  const float4* w4 = reinterpret_cast<const float4*>(W + (size_t)(h*64 + d)*E_ + p*64 + j*16);
  float4 wa = w4[0], wb = w4[1], wcv = w4[2], wd = w4[3];
  for (int r = 0; r < R; ++r){
    int e = list[h*SLOTS + r];
    int b = e >> 11, rr = e & 2047;
    int row = (z == 0) ? rr : tmap[b*S_ + rr];
    const float4* x4 = reinterpret_cast<const float4*>(x + (size_t)(b*S_ + row)*E_ + p*64 + j*16);
    float acc = dot4(x4[0], wa) + dot4(x4[1], wb) + dot4(x4[2], wcv) + dot4(x4[3], wd);
    acc += __shfl_xor(acc, 1);
    acc += __shfl_xor(acc, 2);
    if (j == 0) atomicAdd(&dst[(size_t)(h*SLOTS + r)*64 + d], acc);
  }
}

// ---------------- exact d2 + survivor build ----------------
__global__ __launch_bounds__(256) void d2_survive_k(
    const unsigned* __restrict__ cnt, const unsigned* __restrict__ cand,
    const int* __restrict__ qslotm, const int* __restrict__ kslotm,
    const float* __restrict__ qex, const float* __restrict__ kex,
    unsigned* __restrict__ scnt, uint2* __restrict__ surv){
  unsigned n = *cnt; if (n > MAXCAND) n = MAXCAND;
  int wid = threadIdx.x >> 6, lane = threadIdx.x & 63;
  for (unsigned i = blockIdx.x*4 + wid; i < n; i += gridDim.x*4){
    unsigned u = cand[i];
    int b = (int)(u >> 26), h = (int)((u >> 22) & 15);
    int s = (int)((u >> 11) & 2047), tc = (int)(u & 2047);
    int qi = ((b*16 + h) << 11) | s, ki = ((b*16 + h) << 11) | tc;
    int qs = qslotm[qi], ks = kslotm[ki];
    float sq;
    if (qs >= 0 && ks >= 0){
      float a = qex[(size_t)(h*SLOTS + qs)*64 + lane] - kex[(size_t)(h*SLOTS + ks)*64 + lane];
      sq = a*a;
    } else sq = 1e30f;
    #pragma unroll
    for (int o = 32; o; o >>= 1) sq += __shfl_xor(sq, o);
    if (lane == 0 && sq < T_CUT){
      unsigned si = atomicAdd(scnt, 1u);
      if (si < MAXSURV){
        uint2 sv;
        sv.x = ((unsigned)b << 24) | ((unsigned)h << 20) | ((unsigned)s << 9) | (unsigned)ks;
        sv.y = __float_as_uint(expf(-sq));
        surv[si] = sv;
      }
    }
  }
}

// ---------------- scatter: out[b,s,:] += w * (v @ Wo^T) ----------------
__global__ __launch_bounds__(256) void scatter_k(
    const float* __restrict__ Wo, const float* __restrict__ vex,
    const unsigned* __restrict__ scnt, const uint2* __restrict__ surv,
    float* __restrict__ out){
  __shared__ float vsh[64];
  unsigned n = *scnt; if (n > MAXSURV) n = MAXSURV;
  unsigned items = n*4;
  for (unsigned it = blockIdx.x; it < items; it += gridDim.x){
    __syncthreads();
    uint2 sv = surv[it >> 2];
    int c = (int)(it & 3);
    int b = (int)(sv.x >> 24), h = (int)((sv.x >> 20) & 15);
    int s = (int)((sv.x >> 9) & 2047), ks = (int)(sv.x & 511);
    float w = __uint_as_float(sv.y);
    if (threadIdx.x < 64) vsh[threadIdx.x] = vex[(size_t)(h*SLOTS + ks)*64 + threadIdx.x];
    __syncthreads();
    int e = c*256 + threadIdx.x;
    const float4* wo4 = reinterpret_cast<const float4*>(Wo + (size_t)e*E_ + h*64);
    const float4* vv4 = reinterpret_cast<const float4*>(vsh);
    float a = 0.f;
    #pragma unroll
    for (int d2 = 0; d2 < 16; ++d2){
      float4 vv = vv4[d2], ww = wo4[d2];
      a += vv.x*ww.x + vv.y*ww.y + vv.z*ww.z + vv.w*ww.w;
    }
    atomicAdd(&out[(size_t)(b*S_ + s)*E_ + e], w*a);
  }
}

extern "C" void kernel_launch(void* const* d_in, const int* in_sizes, int n_in,
                              void* d_out, int out_size, void* d_ws, size_t ws_size,
                              hipStream_t stream){
  const float* x  = (const float*)d_in[0];
  const int* mask = (const int*)d_in[1];
  const float* Wq = (const float*)d_in[2];
  const float* Wk = (const float*)d_in[3];
  const float* Wv = (const float*)d_in[4];
  const float* Wo = (const float*)d_in[5];
  float* out = (float*)d_out;

  char* w = (char*)d_ws;
  unsigned short* Qhm = (unsigned short*)w; w += (size_t)BS_*E_*2;   // head-major [b,h][s][64]
  unsigned short* Kc  = (unsigned short*)w; w += (size_t)BS_*E_*2;   // head-major compacted K
  unsigned short* xb  = (unsigned short*)w; w += (size_t)BS_*E_*2;   // bf16 x, row-major
  unsigned short* Wqkb = (unsigned short*)w; w += (size_t)E_*E_*2*2; // Wq | Wk bf16
  float* qn  = (float*)w; w += (size_t)BHS_*4;
  float* knc = (float*)w; w += (size_t)BHS_*4;
  int* tmap   = (int*)w; w += (size_t)BS_*4;
  int* vcount = (int*)w; w += 256;
  unsigned* cand = (unsigned*)w; w += (size_t)MAXCAND*4;
  int* qslotm = (int*)w; w += (size_t)BHS_*4;
  int* kslotm = (int*)w; w += (size_t)BHS_*4;
  int* qlist  = (int*)w; w += (size_t)H_*SLOTS*4;
  int* klist  = (int*)w; w += (size_t)H_*SLOTS*4;
  uint2* surv = (uint2*)w; w += (size_t)MAXSURV*8;
  // ---- contiguous zeroed region (single memset): counters, flags, exact rows
  char* zbase = w;
  unsigned* cnt  = (unsigned*)w; w += 256;
  unsigned* scnt = (unsigned*)w; w += 256;
  int* lcnt = (int*)w; w += 256;
  int* qflag  = (int*)w; w += (size_t)BHS_*4;
  int* kflag  = (int*)w; w += (size_t)BHS_*4;
  float* qex = (float*)w; w += (size_t)H_*SLOTS*64*4;
  float* kex = (float*)w; w += (size_t)H_*SLOTS*64*4;
  float* vex = (float*)w; w += (size_t)H_*SLOTS*64*4;
  size_t zbytes = (size_t)(w - zbase);

  hipMemsetAsync(d_out, 0, (size_t)out_size*sizeof(float), stream);
  hipMemsetAsync(zbase, 0, zbytes, stream);

  // casts + mask compaction (one launch)
  cast_compact_k<<<5124, 256, 0, stream>>>(x, Wq, Wk, mask, xb, Wqkb, tmap, vcount);

  // fused Q|K projection, head-major out, norms in epilogue (one launch)
  proj_hm_k<<<dim3(64, 8, 2), 256, 0, stream>>>(xb, Wqkb, tmap, vcount, Qhm, Kc, qn, knc);

  // register-resident pair search (tiny test loop + cold emit pass)
  search_k<<<16*64, 256, 0, stream>>>(Qhm, Kc, qn, knc, vcount, cnt, cand, qflag, kflag);

  // sparse exact pipeline
  rowlist_k<<<dim3(BHS_/256, 2), 256, 0, stream>>>(qflag, kflag, lcnt, qlist, klist, qslotm, kslotm);
  exact_rows_k<<<dim3(16, 16, 3), 256, 0, stream>>>(x, tmap, Wq, Wk, Wv, lcnt, qlist, klist, qex, kex, vex);
  d2_survive_k<<<256, 256, 0, stream>>>(cnt, cand, qslotm, kslotm, qex, kex, scnt, surv);
  scatter_k<<<512, 256, 0, stream>>>(Wo, vex, scnt, surv, out);
}

// Round 10
// 189.674 us; speedup vs baseline: 1.5216x; 1.5216x over previous
//
#include <hip/hip_runtime.h>
#include <hip/hip_bf16.h>
#include <cstdint>
#include <cstddef>

#define B_ 4
#define S_ 2048
#define E_ 1024
#define H_ 16
#define BS_ (B_*S_)
#define BHS_ (B_*H_*S_)
#define MAXCAND (1u<<18)
#define MAXSURV 8192
#define SLOTS 512

static constexpr float T_SEARCH = 50.0f;  // bf16 search threshold (~4.5-sigma over cut)
static constexpr float T_CUT    = 48.5f;  // exact fp32 cut; e^-48.5 contribution ~300x under tol

typedef __attribute__((ext_vector_type(8))) short bf16x8;
typedef __attribute__((ext_vector_type(4))) float f32x4;

static __device__ __forceinline__ unsigned short f32_to_bf16(float f){
  unsigned u = __float_as_uint(f);
  return (unsigned short)((u + 0x7fffu + ((u >> 16) & 1u)) >> 16);  // RNE
}
static __device__ __forceinline__ void gload_lds16(const void* g, void* l){
  __builtin_amdgcn_global_load_lds(
      (const __attribute__((address_space(1))) unsigned int*)g,
      (__attribute__((address_space(3))) unsigned int*)l, 16, 0, 0);
}
static __device__ __forceinline__ float dot4(float4 a, float4 b){
  return a.x*b.x + a.y*b.y + a.z*b.z + a.w*b.w;
}

// ------- fused: f32->bf16 casts (x, Wq, Wk) + per-batch mask compaction -------
__global__ void cast_compact_k(const float* __restrict__ x,
                               const float* __restrict__ wq, const float* __restrict__ wk,
                               const int* __restrict__ mask,
                               unsigned short* __restrict__ xb, unsigned short* __restrict__ wqkb,
                               int* __restrict__ tmap, int* __restrict__ vcount){
  int blk = blockIdx.x;
  if (blk >= 5120){                     // mask compaction, b = blk-5120
    int b = blk - 5120, tid = threadIdx.x;
    __shared__ int ps[256];
    int loc[8]; int cnt = 0;
    #pragma unroll
    for (int j = 0; j < 8; ++j){ int m = mask[b*S_ + tid*8 + j]; loc[j] = m; cnt += m; }
    ps[tid] = cnt; __syncthreads();
    for (int off = 1; off < 256; off <<= 1){
      int v = (tid >= off) ? ps[tid-off] : 0;
      __syncthreads(); ps[tid] += v; __syncthreads();
    }
    int base = ps[tid] - cnt;
    #pragma unroll
    for (int j = 0; j < 8; ++j)
      if (loc[j]){ tmap[b*S_ + base] = tid*8 + j; ++base; }
    if (tid == 255) vcount[b] = ps[255];
    return;
  }
  const float* src; unsigned short* dst; int base;
  if (blk < 4096){ src = x;  dst = xb;                  base = blk; }
  else if (blk < 4608){ src = wq; dst = wqkb;           base = blk - 4096; }
  else { src = wk; dst = wqkb + (size_t)E_*E_;          base = blk - 4608; }
  size_t i = (size_t)base*256 + threadIdx.x;            // 8 elems per item
  const float4* s4 = reinterpret_cast<const float4*>(src) + 2*i;
  float4 a = s4[0], b = s4[1];
  float v[8] = {a.x,a.y,a.z,a.w,b.x,b.y,b.z,b.w};
  union { unsigned short us[8]; uint4 u4; } o;
  #pragma unroll
  for (int j = 0; j < 8; ++j) o.us[j] = f32_to_bf16(v[j]);
  reinterpret_cast<uint4*>(dst)[i] = o.u4;
}

// ------- fused Q|K projection, head-major out, norms in epilogue -------
__global__ __launch_bounds__(256) void proj_hm_k(
    const unsigned short* __restrict__ xb,
    const unsigned short* __restrict__ Wqkb,
    const int* __restrict__ tmap, const int* __restrict__ vcount,
    unsigned short* __restrict__ Qhm, unsigned short* __restrict__ Kc,
    float* __restrict__ qn, float* __restrict__ knc){
  const int z = blockIdx.z;
  const int m0 = blockIdx.x * 128, n0 = blockIdx.y * 128;
  const int bb = m0 >> 11, tc0 = m0 & 2047;
  const int vc = vcount[bb];
  if (z == 1 && tc0 >= vc) return;
  const unsigned short* Bw = Wqkb + (size_t)z*E_*E_;
  unsigned short* Out = z ? Kc : Qhm;
  float* Nrm = z ? knc : qn;

  __shared__ unsigned short At[128*64];
  __shared__ unsigned short Bt[128*64];
  const int tid = threadIdx.x, wave = tid >> 6, lane = tid & 63;
  const int wr = wave >> 1, wc = wave & 1;
  const int fr = lane & 15, fc = lane >> 4;
  const int srow = lane >> 3, sc = lane & 7;

  int arow[4];
  #pragma unroll
  for (int i = 0; i < 4; ++i){
    int r = wave*32 + i*8 + srow;
    int tc = tc0 + r;
    arow[i] = z ? ((tc < vc) ? tmap[bb*S_ + tc] : 0) : tc;
  }

  f32x4 acc[4][4] = {};

  for (int k0 = 0; k0 < 1024; k0 += 64){
    #pragma unroll
    for (int i = 0; i < 4; ++i){
      int r  = wave*32 + i*8 + srow;
      int cs = sc ^ (r & 7);
      gload_lds16(xb + ((size_t)(bb << 11) + arow[i])*1024 + k0 + cs*8, &At[(wave*32 + i*8)*64]);
      gload_lds16(Bw + (size_t)(n0 + r)*1024 + k0 + cs*8, &Bt[(wave*32 + i*8)*64]);
    }
    __syncthreads();
    #pragma unroll
    for (int kk = 0; kk < 2; ++kk){
      bf16x8 af[4], bf_[4];
      #pragma unroll
      for (int mf = 0; mf < 4; ++mf){
        int r = wr*64 + mf*16 + fr;
        af[mf] = *reinterpret_cast<const bf16x8*>(&At[r*64 + ((kk*4 + fc) ^ (r & 7))*8]);
      }
      #pragma unroll
      for (int nf = 0; nf < 4; ++nf){
        int r = wc*64 + nf*16 + fr;
        bf_[nf] = *reinterpret_cast<const bf16x8*>(&Bt[r*64 + ((kk*4 + fc) ^ (r & 7))*8]);
      }
      #pragma unroll
      for (int mf = 0; mf < 4; ++mf)
        #pragma unroll
        for (int nf = 0; nf < 4; ++nf)
          acc[mf][nf] = __builtin_amdgcn_mfma_f32_16x16x32_bf16(af[mf], bf_[nf], acc[mf][nf], 0, 0, 0);
    }
    __syncthreads();
  }

  const int h = (n0 >> 6) + wc;
  const size_t rowbase = (size_t)((bb << 4) | h)*S_;
  #pragma unroll
  for (int mf = 0; mf < 4; ++mf)
    #pragma unroll
    for (int r = 0; r < 4; ++r){
      int rowb = tc0 + wr*64 + mf*16 + fc*4 + r;
      #pragma unroll
      for (int nf = 0; nf < 4; ++nf)
        Out[(rowbase + rowb)*64 + nf*16 + fr] = f32_to_bf16(acc[mf][nf][r]);
      float s = 0.f;
      #pragma unroll
      for (int nf = 0; nf < 4; ++nf) s += acc[mf][nf][r]*acc[mf][nf][r];
      s += __shfl_xor(s, 1); s += __shfl_xor(s, 2);
      s += __shfl_xor(s, 4); s += __shfl_xor(s, 8);
      if (fr == 0) Nrm[rowbase + rowb] = s;
    }
}

// ------- LDS-ring candidate search (T3/T4: shared staging, counted vmcnt) -------
// Block: 128-row Q strip of one bh; K streams in 64-key chunks through a 3-slot
// LDS ring via global_load_lds (4-wave shared). Raw s_barrier (no vmcnt(0) drain),
// main-loop wait = vmcnt(2) (one stage outstanding), peeled 2-iteration tail.
#define VMW(N_) asm volatile("s_waitcnt vmcnt(" #N_ ")" ::: "memory")
#define BAR()  do{ __builtin_amdgcn_s_barrier(); __builtin_amdgcn_sched_barrier(0); }while(0)

#define STAGE_K(slot_, c_) do{                                                 \
  _Pragma("unroll") for (int j_ = 0; j_ < 2; ++j_){                            \
    int rr_ = wave*16 + j_*8 + srow;                                           \
    gload_lds16(Kh + (size_t)((c_)*64 + rr_)*64 + (sc ^ (rr_ & 7))*8,          \
                &Kt[slot_][(wave*16 + j_*8)*64]);                              \
  }                                                                            \
}while(0)

#define COMPUTE(slot_, c_) do{                                                 \
  int t0_ = (c_)*64;                                                           \
  bf16x8 af_[2][2], bfr_[4][2]; float knh_[4];                                 \
  _Pragma("unroll") for (int mf_ = 0; mf_ < 2; ++mf_)                          \
  _Pragma("unroll") for (int kk_ = 0; kk_ < 2; ++kk_){                         \
    int r_ = wave*32 + mf_*16 + fr;                                            \
    af_[mf_][kk_] = *reinterpret_cast<const bf16x8*>(                          \
        &Qt[r_*64 + (((kk_*4 + fc) ^ (r_ & 7))*8)]);                           \
  }                                                                            \
  _Pragma("unroll") for (int nf_ = 0; nf_ < 4; ++nf_){                         \
    int tl_ = nf_*16 + fr;                                                     \
    _Pragma("unroll") for (int kk_ = 0; kk_ < 2; ++kk_)                        \
      bfr_[nf_][kk_] = *reinterpret_cast<const bf16x8*>(                       \
          &Kt[slot_][tl_*64 + (((kk_*4 + fc) ^ (tl_ & 7))*8)]);                \
    int t_ = t0_ + tl_;                                                        \
    knh_[nf_] = (t_ < vc) ? 0.5f*knl[t_] : 1e30f;                              \
  }                                                                            \
  f32x4 acc[2][4];                                                             \
  _Pragma("unroll") for (int mf_ = 0; mf_ < 2; ++mf_)                          \
  _Pragma("unroll") for (int nf_ = 0; nf_ < 4; ++nf_){                         \
    acc[mf_][nf_] = __builtin_amdgcn_mfma_f32_16x16x32_bf16(                   \
        af_[mf_][0], bfr_[nf_][0], z4, 0, 0, 0);                               \
    acc[mf_][nf_] = __builtin_amdgcn_mfma_f32_16x16x32_bf16(                   \
        af_[mf_][1], bfr_[nf_][1], acc[mf_][nf_], 0, 0, 0);                    \
  }                                                                            \
  f32x4 m4 = acc[0][0];                                                        \
  _Pragma("unroll") for (int mf_ = 0; mf_ < 2; ++mf_)                          \
  _Pragma("unroll") for (int nf_ = 0; nf_ < 4; ++nf_)                          \
    if (mf_ || nf_){                                                           \
      _Pragma("unroll") for (int r_ = 0; r_ < 4; ++r_)                         \
        m4[r_] = fmaxf(m4[r_], acc[mf_][nf_][r_]);                             \
    }                                                                          \
  float mx = fmaxf(fmaxf(m4[0], m4[1]), fmaxf(m4[2], m4[3]));                  \
  float knmin = fminf(fminf(knh_[0], knh_[1]), fminf(knh_[2], knh_[3]));       \
  if (__any(mx > qamin + knmin)){                                              \
    _Pragma("unroll") for (int mf_ = 0; mf_ < 2; ++mf_)                        \
    _Pragma("unroll") for (int nf_ = 0; nf_ < 4; ++nf_)                        \
    _Pragma("unroll") for (int r_ = 0; r_ < 4; ++r_){                          \
      if (acc[mf_][nf_][r_] > qa[mf_*4+r_] + knh_[nf_]){                       \
        int t_ = t0_ + nf_*16 + fr;                                            \
        if (t_ < vc){                                                          \
          int s_ = s0 + wave*32 + mf_*16 + fc*4 + r_;                          \
          unsigned idx_ = atomicAdd(cnt, 1u);                                  \
          if (idx_ < MAXCAND)                                                  \
            cand[idx_] = ((unsigned)b << 26) | ((unsigned)h << 22)             \
                       | ((unsigned)s_ << 11) | (unsigned)t_;                  \
          qflag[(bh << 11) | s_] = 1;                                          \
          kflag[(bh << 11) | t_] = 1;                                          \
        }                                                                      \
      }                                                                        \
    }                                                                          \
  }                                                                            \
}while(0)

__global__ __launch_bounds__(256) void search_k(
    const unsigned short* __restrict__ Qhm, const unsigned short* __restrict__ Kc,
    const float* __restrict__ qn, const float* __restrict__ knc,
    const int* __restrict__ vcount,
    unsigned* __restrict__ cnt, unsigned* __restrict__ cand,
    int* __restrict__ qflag, int* __restrict__ kflag){
  __shared__ unsigned short Qt[128*64];      // 16KB
  __shared__ unsigned short Kt[3][64*64];    // 24KB ring
  __shared__ float knl[S_];                  // 8KB
  const int wave = threadIdx.x >> 6, lane = threadIdx.x & 63;
  const int bh = blockIdx.x & 63;
  const int s0 = (blockIdx.x >> 6) * 128;    // 16 strip-blocks
  const int b = bh >> 4, h = bh & 15;
  const int vc = vcount[b];
  const int nt = (vc + 63) >> 6;
  if (nt == 0) return;
  const int fr = lane & 15, fc = lane >> 4;
  const int srow = lane >> 3, sc = lane & 7;
  const unsigned short* Qh = Qhm + (size_t)bh*S_*64;
  const unsigned short* Kh = Kc + (size_t)bh*S_*64;
  const float* qnb = qn + (size_t)bh*S_;
  const float* knb = knc + (size_t)bh*S_;
  const f32x4 z4 = {0.f, 0.f, 0.f, 0.f};

  // qa thresholds: force-complete BEFORE staging so compiler VM loads don't
  // pollute the hand-counted vmcnt bookkeeping.
  float qa[8];
  #pragma unroll
  for (int mf = 0; mf < 2; ++mf)
    #pragma unroll
    for (int r = 0; r < 4; ++r)
      qa[mf*4+r] = 0.5f*(qnb[s0 + wave*32 + mf*16 + fc*4 + r] - T_SEARCH);
  float qamin = qa[0];
  #pragma unroll
  for (int j = 1; j < 8; ++j) qamin = fminf(qamin, qa[j]);
  asm volatile("" :: "v"(qamin));
  asm volatile("s_waitcnt vmcnt(0)" ::: "memory");
  __builtin_amdgcn_sched_barrier(0);

  // ---- prologue staging: Q strip (4 ops) + kn row (2 ops) + K0,K1 (2 ops each)
  #pragma unroll
  for (int i = 0; i < 4; ++i){
    int r = wave*32 + i*8 + srow;
    gload_lds16(Qh + (size_t)(s0 + r)*64 + (sc ^ (r & 7))*8, &Qt[(wave*32 + i*8)*64]);
  }
  gload_lds16(knb + wave*512 + lane*4,       &knl[wave*512]);
  gload_lds16(knb + wave*512 + 256 + lane*4, &knl[wave*512 + 256]);
  STAGE_K(0, 0);
  if (nt > 1) STAGE_K(1, 1);

  int c = 0, sl = 0;
  for (; c + 2 < nt; ++c){
    VMW(2); BAR();                       // own stage(c) retired; all waves synced
    int sl2 = sl + 2; if (sl2 >= 3) sl2 -= 3;
    STAGE_K(sl2, c + 2);                 // after barrier: ring-3 WAR-safe
    COMPUTE(sl, c);
    ++sl; if (sl == 3) sl = 0;
  }
  if (c + 1 < nt){ VMW(2); BAR(); COMPUTE(sl, c); ++c; ++sl; if (sl == 3) sl = 0; }
  VMW(0); BAR(); COMPUTE(sl, c);
}

// ---------------- build per-head row lists + slot maps ----------------
__global__ void rowlist_k(const int* __restrict__ qflag, const int* __restrict__ kflag,
                          int* __restrict__ lcnt,
                          int* __restrict__ qlist, int* __restrict__ klist,
                          int* __restrict__ qslotm, int* __restrict__ kslotm){
  int side = blockIdx.y;
  int i = blockIdx.x*256 + threadIdx.x;
  const int* flag = side ? kflag : qflag;
  if (!flag[i]) return;
  int h = (i >> 11) & 15, b = i >> 15, row = i & 2047;
  int slot = atomicAdd(&lcnt[side*16 + h], 1);
  int* list = side ? klist : qlist;
  int* sm   = side ? kslotm : qslotm;
  if (slot < SLOTS){ list[h*SLOTS + slot] = (b << 11) | row; sm[i] = slot; }
  else sm[i] = -1;
}

// ---------------- exact fp32 rows, head-grouped, E-part-split ----------------
__global__ __launch_bounds__(256) void exact_rows_k(
    const float* __restrict__ x, const int* __restrict__ tmap,
    const float* __restrict__ Wq, const float* __restrict__ Wk,
    const float* __restrict__ Wv,
    const int* __restrict__ lcnt,
    const int* __restrict__ qlist, const int* __restrict__ klist,
    float* __restrict__ qex, float* __restrict__ kex, float* __restrict__ vex){
  int p = blockIdx.x, h = blockIdx.y, z = blockIdx.z;
  int R = lcnt[(z == 0 ? 0 : 16) + h]; if (R > SLOTS) R = SLOTS;
  if (R == 0) return;
  const float* W = (z == 0) ? Wq : (z == 1 ? Wk : Wv);
  const int* list = (z == 0) ? qlist : klist;
  float* dst = (z == 0) ? qex : (z == 1 ? kex : vex);
  int d = threadIdx.x >> 2, j = threadIdx.x & 3;
  const float4* w4 = reinterpret_cast<const float4*>(W + (size_t)(h*64 + d)*E_ + p*64 + j*16);
  float4 wa = w4[0], wb = w4[1], wcv = w4[2], wd = w4[3];
  for (int r = 0; r < R; ++r){
    int e = list[h*SLOTS + r];
    int b = e >> 11, rr = e & 2047;
    int row = (z == 0) ? rr : tmap[b*S_ + rr];
    const float4* x4 = reinterpret_cast<const float4*>(x + (size_t)(b*S_ + row)*E_ + p*64 + j*16);
    float acc = dot4(x4[0], wa) + dot4(x4[1], wb) + dot4(x4[2], wcv) + dot4(x4[3], wd);
    acc += __shfl_xor(acc, 1);
    acc += __shfl_xor(acc, 2);
    if (j == 0) atomicAdd(&dst[(size_t)(h*SLOTS + r)*64 + d], acc);
  }
}

// ---------------- exact d2 + survivor build ----------------
__global__ __launch_bounds__(256) void d2_survive_k(
    const unsigned* __restrict__ cnt, const unsigned* __restrict__ cand,
    const int* __restrict__ qslotm, const int* __restrict__ kslotm,
    const float* __restrict__ qex, const float* __restrict__ kex,
    unsigned* __restrict__ scnt, uint2* __restrict__ surv){
  unsigned n = *cnt; if (n > MAXCAND) n = MAXCAND;
  int wid = threadIdx.x >> 6, lane = threadIdx.x & 63;
  for (unsigned i = blockIdx.x*4 + wid; i < n; i += gridDim.x*4){
    unsigned u = cand[i];
    int b = (int)(u >> 26), h = (int)((u >> 22) & 15);
    int s = (int)((u >> 11) & 2047), tc = (int)(u & 2047);
    int qi = ((b*16 + h) << 11) | s, ki = ((b*16 + h) << 11) | tc;
    int qs = qslotm[qi], ks = kslotm[ki];
    float sq;
    if (qs >= 0 && ks >= 0){
      float a = qex[(size_t)(h*SLOTS + qs)*64 + lane] - kex[(size_t)(h*SLOTS + ks)*64 + lane];
      sq = a*a;
    } else sq = 1e30f;
    #pragma unroll
    for (int o = 32; o; o >>= 1) sq += __shfl_xor(sq, o);
    if (lane == 0 && sq < T_CUT){
      unsigned si = atomicAdd(scnt, 1u);
      if (si < MAXSURV){
        uint2 sv;
        sv.x = ((unsigned)b << 24) | ((unsigned)h << 20) | ((unsigned)s << 9) | (unsigned)ks;
        sv.y = __float_as_uint(expf(-sq));
        surv[si] = sv;
      }
    }
  }
}

// ---------------- scatter: out[b,s,:] += w * (v @ Wo^T) ----------------
__global__ __launch_bounds__(256) void scatter_k(
    const float* __restrict__ Wo, const float* __restrict__ vex,
    const unsigned* __restrict__ scnt, const uint2* __restrict__ surv,
    float* __restrict__ out){
  __shared__ float vsh[64];
  unsigned n = *scnt; if (n > MAXSURV) n = MAXSURV;
  unsigned items = n*4;
  for (unsigned it = blockIdx.x; it < items; it += gridDim.x){
    __syncthreads();
    uint2 sv = surv[it >> 2];
    int c = (int)(it & 3);
    int b = (int)(sv.x >> 24), h = (int)((sv.x >> 20) & 15);
    int s = (int)((sv.x >> 9) & 2047), ks = (int)(sv.x & 511);
    float w = __uint_as_float(sv.y);
    if (threadIdx.x < 64) vsh[threadIdx.x] = vex[(size_t)(h*SLOTS + ks)*64 + threadIdx.x];
    __syncthreads();
    int e = c*256 + threadIdx.x;
    const float4* wo4 = reinterpret_cast<const float4*>(Wo + (size_t)e*E_ + h*64);
    const float4* vv4 = reinterpret_cast<const float4*>(vsh);
    float a = 0.f;
    #pragma unroll
    for (int d2 = 0; d2 < 16; ++d2){
      float4 vv = vv4[d2], ww = wo4[d2];
      a += vv.x*ww.x + vv.y*ww.y + vv.z*ww.z + vv.w*ww.w;
    }
    atomicAdd(&out[(size_t)(b*S_ + s)*E_ + e], w*a);
  }
}

extern "C" void kernel_launch(void* const* d_in, const int* in_sizes, int n_in,
                              void* d_out, int out_size, void* d_ws, size_t ws_size,
                              hipStream_t stream){
  const float* x  = (const float*)d_in[0];
  const int* mask = (const int*)d_in[1];
  const float* Wq = (const float*)d_in[2];
  const float* Wk = (const float*)d_in[3];
  const float* Wv = (const float*)d_in[4];
  const float* Wo = (const float*)d_in[5];
  float* out = (float*)d_out;

  char* w = (char*)d_ws;
  unsigned short* Qhm = (unsigned short*)w; w += (size_t)BS_*E_*2;   // head-major [b,h][s][64]
  unsigned short* Kc  = (unsigned short*)w; w += (size_t)BS_*E_*2;   // head-major compacted K
  unsigned short* xb  = (unsigned short*)w; w += (size_t)BS_*E_*2;   // bf16 x, row-major
  unsigned short* Wqkb = (unsigned short*)w; w += (size_t)E_*E_*2*2; // Wq | Wk bf16
  float* qn  = (float*)w; w += (size_t)BHS_*4;
  float* knc = (float*)w; w += (size_t)BHS_*4;
  int* tmap   = (int*)w; w += (size_t)BS_*4;
  int* vcount = (int*)w; w += 256;
  unsigned* cand = (unsigned*)w; w += (size_t)MAXCAND*4;
  int* qslotm = (int*)w; w += (size_t)BHS_*4;
  int* kslotm = (int*)w; w += (size_t)BHS_*4;
  int* qlist  = (int*)w; w += (size_t)H_*SLOTS*4;
  int* klist  = (int*)w; w += (size_t)H_*SLOTS*4;
  uint2* surv = (uint2*)w; w += (size_t)MAXSURV*8;
  // ---- contiguous zeroed region (single memset): counters, flags, exact rows
  char* zbase = w;
  unsigned* cnt  = (unsigned*)w; w += 256;
  unsigned* scnt = (unsigned*)w; w += 256;
  int* lcnt = (int*)w; w += 256;
  int* qflag  = (int*)w; w += (size_t)BHS_*4;
  int* kflag  = (int*)w; w += (size_t)BHS_*4;
  float* qex = (float*)w; w += (size_t)H_*SLOTS*64*4;
  float* kex = (float*)w; w += (size_t)H_*SLOTS*64*4;
  float* vex = (float*)w; w += (size_t)H_*SLOTS*64*4;
  size_t zbytes = (size_t)(w - zbase);

  hipMemsetAsync(d_out, 0, (size_t)out_size*sizeof(float), stream);
  hipMemsetAsync(zbase, 0, zbytes, stream);

  // casts + mask compaction (one launch)
  cast_compact_k<<<5124, 256, 0, stream>>>(x, Wq, Wk, mask, xb, Wqkb, tmap, vcount);

  // fused Q|K projection, head-major out, norms in epilogue (one launch)
  proj_hm_k<<<dim3(64, 8, 2), 256, 0, stream>>>(xb, Wqkb, tmap, vcount, Qhm, Kc, qn, knc);

  // LDS-ring pair search (T3/T4 counted-vmcnt pipeline)
  search_k<<<16*64, 256, 0, stream>>>(Qhm, Kc, qn, knc, vcount, cnt, cand, qflag, kflag);

  // sparse exact pipeline
  rowlist_k<<<dim3(BHS_/256, 2), 256, 0, stream>>>(qflag, kflag, lcnt, qlist, klist, qslotm, kslotm);
  exact_rows_k<<<dim3(16, 16, 3), 256, 0, stream>>>(x, tmap, Wq, Wk, Wv, lcnt, qlist, klist, qex, kex, vex);
  d2_survive_k<<<256, 256, 0, stream>>>(cnt, cand, qslotm, kslotm, qex, kex, scnt, surv);
  scatter_k<<<512, 256, 0, stream>>>(Wo, vex, scnt, surv, out);
}

// Round 11
// 174.906 us; speedup vs baseline: 1.6501x; 1.0844x over previous
//
#include <hip/hip_runtime.h>
#include <hip/hip_bf16.h>
#include <cstdint>
#include <cstddef>

#define B_ 4
#define S_ 2048
#define E_ 1024
#define H_ 16
#define BS_ (B_*S_)
#define BHS_ (B_*H_*S_)
#define MAXCAND (1u<<18)
#define MAXSURV 8192
#define SLOTS 512

static constexpr float T_SEARCH = 50.0f;  // bf16 search threshold (~4.5-sigma over cut)
static constexpr float T_CUT    = 48.5f;  // exact fp32 cut; e^-48.5 contribution ~300x under tol

typedef __attribute__((ext_vector_type(8))) short bf16x8;
typedef __attribute__((ext_vector_type(4))) float f32x4;

static __device__ __forceinline__ unsigned short f32_to_bf16(float f){
  unsigned u = __float_as_uint(f);
  return (unsigned short)((u + 0x7fffu + ((u >> 16) & 1u)) >> 16);  // RNE
}
static __device__ __forceinline__ void gload_lds16(const void* g, void* l){
  __builtin_amdgcn_global_load_lds(
      (const __attribute__((address_space(1))) unsigned int*)g,
      (__attribute__((address_space(3))) unsigned int*)l, 16, 0, 0);
}
static __device__ __forceinline__ float dot4(float4 a, float4 b){
  return a.x*b.x + a.y*b.y + a.z*b.z + a.w*b.w;
}

// ------- fused: f32->bf16 casts (x, Wq, Wk) + per-batch mask compaction -------
__global__ void cast_compact_k(const float* __restrict__ x,
                               const float* __restrict__ wq, const float* __restrict__ wk,
                               const int* __restrict__ mask,
                               unsigned short* __restrict__ xb, unsigned short* __restrict__ wqkb,
                               int* __restrict__ tmap, int* __restrict__ vcount){
  int blk = blockIdx.x;
  if (blk >= 5120){                     // mask compaction, b = blk-5120
    int b = blk - 5120, tid = threadIdx.x;
    __shared__ int ps[256];
    int loc[8]; int cnt = 0;
    #pragma unroll
    for (int j = 0; j < 8; ++j){ int m = mask[b*S_ + tid*8 + j]; loc[j] = m; cnt += m; }
    ps[tid] = cnt; __syncthreads();
    for (int off = 1; off < 256; off <<= 1){
      int v = (tid >= off) ? ps[tid-off] : 0;
      __syncthreads(); ps[tid] += v; __syncthreads();
    }
    int base = ps[tid] - cnt;
    #pragma unroll
    for (int j = 0; j < 8; ++j)
      if (loc[j]){ tmap[b*S_ + base] = tid*8 + j; ++base; }
    if (tid == 255) vcount[b] = ps[255];
    return;
  }
  const float* src; unsigned short* dst; int base;
  if (blk < 4096){ src = x;  dst = xb;                  base = blk; }
  else if (blk < 4608){ src = wq; dst = wqkb;           base = blk - 4096; }
  else { src = wk; dst = wqkb + (size_t)E_*E_;          base = blk - 4608; }
  size_t i = (size_t)base*256 + threadIdx.x;            // 8 elems per item
  const float4* s4 = reinterpret_cast<const float4*>(src) + 2*i;
  float4 a = s4[0], b = s4[1];
  float v[8] = {a.x,a.y,a.z,a.w,b.x,b.y,b.z,b.w};
  union { unsigned short us[8]; uint4 u4; } o;
  #pragma unroll
  for (int j = 0; j < 8; ++j) o.us[j] = f32_to_bf16(v[j]);
  reinterpret_cast<uint4*>(dst)[i] = o.u4;
}

// ------- fused Q|K projection, head-major out, norms in epilogue -------
__global__ __launch_bounds__(256) void proj_hm_k(
    const unsigned short* __restrict__ xb,
    const unsigned short* __restrict__ Wqkb,
    const int* __restrict__ tmap, const int* __restrict__ vcount,
    unsigned short* __restrict__ Qhm, unsigned short* __restrict__ Kc,
    float* __restrict__ qn, float* __restrict__ knc){
  const int z = blockIdx.z;
  const int m0 = blockIdx.x * 128, n0 = blockIdx.y * 128;
  const int bb = m0 >> 11, tc0 = m0 & 2047;
  const int vc = vcount[bb];
  if (z == 1 && tc0 >= vc) return;
  const unsigned short* Bw = Wqkb + (size_t)z*E_*E_;
  unsigned short* Out = z ? Kc : Qhm;
  float* Nrm = z ? knc : qn;

  __shared__ unsigned short At[128*64];
  __shared__ unsigned short Bt[128*64];
  const int tid = threadIdx.x, wave = tid >> 6, lane = tid & 63;
  const int wr = wave >> 1, wc = wave & 1;
  const int fr = lane & 15, fc = lane >> 4;
  const int srow = lane >> 3, sc = lane & 7;

  int arow[4];
  #pragma unroll
  for (int i = 0; i < 4; ++i){
    int r = wave*32 + i*8 + srow;
    int tc = tc0 + r;
    arow[i] = z ? ((tc < vc) ? tmap[bb*S_ + tc] : 0) : tc;
  }

  f32x4 acc[4][4] = {};

  for (int k0 = 0; k0 < 1024; k0 += 64){
    #pragma unroll
    for (int i = 0; i < 4; ++i){
      int r  = wave*32 + i*8 + srow;
      int cs = sc ^ (r & 7);
      gload_lds16(xb + ((size_t)(bb << 11) + arow[i])*1024 + k0 + cs*8, &At[(wave*32 + i*8)*64]);
      gload_lds16(Bw + (size_t)(n0 + r)*1024 + k0 + cs*8, &Bt[(wave*32 + i*8)*64]);
    }
    __syncthreads();
    #pragma unroll
    for (int kk = 0; kk < 2; ++kk){
      bf16x8 af[4], bf_[4];
      #pragma unroll
      for (int mf = 0; mf < 4; ++mf){
        int r = wr*64 + mf*16 + fr;
        af[mf] = *reinterpret_cast<const bf16x8*>(&At[r*64 + ((kk*4 + fc) ^ (r & 7))*8]);
      }
      #pragma unroll
      for (int nf = 0; nf < 4; ++nf){
        int r = wc*64 + nf*16 + fr;
        bf_[nf] = *reinterpret_cast<const bf16x8*>(&Bt[r*64 + ((kk*4 + fc) ^ (r & 7))*8]);
      }
      #pragma unroll
      for (int mf = 0; mf < 4; ++mf)
        #pragma unroll
        for (int nf = 0; nf < 4; ++nf)
          acc[mf][nf] = __builtin_amdgcn_mfma_f32_16x16x32_bf16(af[mf], bf_[nf], acc[mf][nf], 0, 0, 0);
    }
    __syncthreads();
  }

  const int h = (n0 >> 6) + wc;
  const size_t rowbase = (size_t)((bb << 4) | h)*S_;
  #pragma unroll
  for (int mf = 0; mf < 4; ++mf)
    #pragma unroll
    for (int r = 0; r < 4; ++r){
      int rowb = tc0 + wr*64 + mf*16 + fc*4 + r;
      #pragma unroll
      for (int nf = 0; nf < 4; ++nf)
        Out[(rowbase + rowb)*64 + nf*16 + fr] = f32_to_bf16(acc[mf][nf][r]);
      float s = 0.f;
      #pragma unroll
      for (int nf = 0; nf < 4; ++nf) s += acc[mf][nf][r]*acc[mf][nf][r];
      s += __shfl_xor(s, 1); s += __shfl_xor(s, 2);
      s += __shfl_xor(s, 4); s += __shfl_xor(s, 8);
      if (fr == 0) Nrm[rowbase + rowb] = s;
    }
}

// ------- LDS-ring candidate search: hot loop is TEST-ONLY, emit deferred -------
#define VMW(N_) asm volatile("s_waitcnt vmcnt(" #N_ ")" ::: "memory")
#define BAR()  do{ __builtin_amdgcn_s_barrier(); __builtin_amdgcn_sched_barrier(0); }while(0)

#define STAGE_K(slot_, c_) do{                                                 \
  _Pragma("unroll") for (int j_ = 0; j_ < 2; ++j_){                            \
    int rr_ = wave*16 + j_*8 + srow;                                           \
    gload_lds16(Kh + (size_t)((c_)*64 + rr_)*64 + (sc ^ (rr_ & 7))*8,          \
                &Kt[slot_][(wave*16 + j_*8)*64]);                              \
  }                                                                            \
}while(0)

// phase A: MFMA + 32 flat compares -> one hitmask bit. No index math, no atomics.
#define TESTCHUNK(slot_, c_) do{                                               \
  int t0_ = (c_)*64;                                                           \
  bf16x8 af_[2][2], bfr_[4][2]; float knh_[4];                                 \
  _Pragma("unroll") for (int mf_ = 0; mf_ < 2; ++mf_)                          \
  _Pragma("unroll") for (int kk_ = 0; kk_ < 2; ++kk_){                         \
    int r_ = wave*32 + mf_*16 + fr;                                            \
    af_[mf_][kk_] = *reinterpret_cast<const bf16x8*>(                          \
        &Qt[r_*64 + (((kk_*4 + fc) ^ (r_ & 7))*8)]);                           \
  }                                                                            \
  _Pragma("unroll") for (int nf_ = 0; nf_ < 4; ++nf_){                         \
    int tl_ = nf_*16 + fr;                                                     \
    _Pragma("unroll") for (int kk_ = 0; kk_ < 2; ++kk_)                        \
      bfr_[nf_][kk_] = *reinterpret_cast<const bf16x8*>(                       \
          &Kt[slot_][tl_*64 + (((kk_*4 + fc) ^ (tl_ & 7))*8)]);                \
    int t_ = t0_ + tl_;                                                        \
    knh_[nf_] = (t_ < vc) ? 0.5f*knl[t_] : 1e30f;                              \
  }                                                                            \
  f32x4 acc[2][4];                                                             \
  _Pragma("unroll") for (int mf_ = 0; mf_ < 2; ++mf_)                          \
  _Pragma("unroll") for (int nf_ = 0; nf_ < 4; ++nf_){                         \
    acc[mf_][nf_] = __builtin_amdgcn_mfma_f32_16x16x32_bf16(                   \
        af_[mf_][0], bfr_[nf_][0], z4, 0, 0, 0);                               \
    acc[mf_][nf_] = __builtin_amdgcn_mfma_f32_16x16x32_bf16(                   \
        af_[mf_][1], bfr_[nf_][1], acc[mf_][nf_], 0, 0, 0);                    \
  }                                                                            \
  int hit_ = 0;                                                                \
  _Pragma("unroll") for (int mf_ = 0; mf_ < 2; ++mf_)                          \
  _Pragma("unroll") for (int nf_ = 0; nf_ < 4; ++nf_)                          \
  _Pragma("unroll") for (int r_ = 0; r_ < 4; ++r_)                             \
    hit_ |= (acc[mf_][nf_][r_] > qa[mf_*4+r_] + knh_[nf_]) ? 1 : 0;            \
  if (__any(hit_)) hitmask |= (1u << (c_));                                    \
}while(0)

// phase B (cold, after loop): reload K chunk from global to regs, redo MFMA, emit.
#define EMITCHUNK(c_) do{                                                      \
  int t0_ = (c_)*64;                                                           \
  bf16x8 af_[2][2], bfr_[4][2]; float knh_[4];                                 \
  _Pragma("unroll") for (int mf_ = 0; mf_ < 2; ++mf_)                          \
  _Pragma("unroll") for (int kk_ = 0; kk_ < 2; ++kk_){                         \
    int r_ = wave*32 + mf_*16 + fr;                                            \
    af_[mf_][kk_] = *reinterpret_cast<const bf16x8*>(                          \
        &Qt[r_*64 + (((kk_*4 + fc) ^ (r_ & 7))*8)]);                           \
  }                                                                            \
  _Pragma("unroll") for (int nf_ = 0; nf_ < 4; ++nf_){                         \
    int tl_ = nf_*16 + fr;                                                     \
    _Pragma("unroll") for (int kk_ = 0; kk_ < 2; ++kk_)                        \
      bfr_[nf_][kk_] = *reinterpret_cast<const bf16x8*>(                       \
          Kh + (size_t)(t0_ + tl_)*64 + (kk_*4 + fc)*8);                       \
    int t_ = t0_ + tl_;                                                        \
    knh_[nf_] = (t_ < vc) ? 0.5f*knl[t_] : 1e30f;                              \
  }                                                                            \
  f32x4 acc[2][4];                                                             \
  _Pragma("unroll") for (int mf_ = 0; mf_ < 2; ++mf_)                          \
  _Pragma("unroll") for (int nf_ = 0; nf_ < 4; ++nf_){                         \
    acc[mf_][nf_] = __builtin_amdgcn_mfma_f32_16x16x32_bf16(                   \
        af_[mf_][0], bfr_[nf_][0], z4, 0, 0, 0);                               \
    acc[mf_][nf_] = __builtin_amdgcn_mfma_f32_16x16x32_bf16(                   \
        af_[mf_][1], bfr_[nf_][1], acc[mf_][nf_], 0, 0, 0);                    \
  }                                                                            \
  _Pragma("unroll") for (int mf_ = 0; mf_ < 2; ++mf_)                          \
  _Pragma("unroll") for (int nf_ = 0; nf_ < 4; ++nf_)                          \
  _Pragma("unroll") for (int r_ = 0; r_ < 4; ++r_){                            \
    if (acc[mf_][nf_][r_] > qa[mf_*4+r_] + knh_[nf_]){                         \
      int t_ = t0_ + nf_*16 + fr;                                              \
      if (t_ < vc){                                                            \
        int s_ = s0 + wave*32 + mf_*16 + fc*4 + r_;                            \
        unsigned idx_ = atomicAdd(cnt, 1u);                                    \
        if (idx_ < MAXCAND)                                                    \
          cand[idx_] = ((unsigned)b << 26) | ((unsigned)h << 22)               \
                     | ((unsigned)s_ << 11) | (unsigned)t_;                    \
        qflag[(bh << 11) | s_] = 1;                                            \
        kflag[(bh << 11) | t_] = 1;                                            \
      }                                                                        \
    }                                                                          \
  }                                                                            \
}while(0)

__global__ __launch_bounds__(256) void search_k(
    const unsigned short* __restrict__ Qhm, const unsigned short* __restrict__ Kc,
    const float* __restrict__ qn, const float* __restrict__ knc,
    const int* __restrict__ vcount,
    unsigned* __restrict__ cnt, unsigned* __restrict__ cand,
    int* __restrict__ qflag, int* __restrict__ kflag){
  __shared__ unsigned short Qt[128*64];      // 16KB
  __shared__ unsigned short Kt[3][64*64];    // 24KB ring
  __shared__ float knl[S_];                  // 8KB
  const int wave = threadIdx.x >> 6, lane = threadIdx.x & 63;
  const int bh = blockIdx.x & 63;
  const int s0 = (blockIdx.x >> 6) * 128;    // 16 strip-blocks
  const int b = bh >> 4, h = bh & 15;
  const int vc = vcount[b];
  const int nt = (vc + 63) >> 6;             // <= 32
  if (nt == 0) return;
  const int fr = lane & 15, fc = lane >> 4;
  const int srow = lane >> 3, sc = lane & 7;
  const unsigned short* Qh = Qhm + (size_t)bh*S_*64;
  const unsigned short* Kh = Kc + (size_t)bh*S_*64;
  const float* qnb = qn + (size_t)bh*S_;
  const float* knb = knc + (size_t)bh*S_;
  const f32x4 z4 = {0.f, 0.f, 0.f, 0.f};

  // qa thresholds: force-complete BEFORE staging so compiler VM loads don't
  // pollute the hand-counted vmcnt bookkeeping.
  float qa[8];
  #pragma unroll
  for (int mf = 0; mf < 2; ++mf)
    #pragma unroll
    for (int r = 0; r < 4; ++r)
      qa[mf*4+r] = 0.5f*(qnb[s0 + wave*32 + mf*16 + fc*4 + r] - T_SEARCH);
  float qamin = qa[0];
  #pragma unroll
  for (int j = 1; j < 8; ++j) qamin = fminf(qamin, qa[j]);
  asm volatile("" :: "v"(qamin));
  asm volatile("s_waitcnt vmcnt(0)" ::: "memory");
  __builtin_amdgcn_sched_barrier(0);

  // ---- prologue staging: Q strip (4 ops) + kn row (2 ops) + K0,K1 (2 ops each)
  #pragma unroll
  for (int i = 0; i < 4; ++i){
    int r = wave*32 + i*8 + srow;
    gload_lds16(Qh + (size_t)(s0 + r)*64 + (sc ^ (r & 7))*8, &Qt[(wave*32 + i*8)*64]);
  }
  gload_lds16(knb + wave*512 + lane*4,       &knl[wave*512]);
  gload_lds16(knb + wave*512 + 256 + lane*4, &knl[wave*512 + 256]);
  STAGE_K(0, 0);
  if (nt > 1) STAGE_K(1, 1);

  unsigned hitmask = 0u;
  int c = 0, sl = 0;
  for (; c + 2 < nt; ++c){
    VMW(2); BAR();                       // own stage(c) retired; all waves synced
    int sl2 = sl + 2; if (sl2 >= 3) sl2 -= 3;
    STAGE_K(sl2, c + 2);                 // after barrier: ring-3 WAR-safe
    TESTCHUNK(sl, c);
    ++sl; if (sl == 3) sl = 0;
  }
  if (c + 1 < nt){ VMW(2); BAR(); TESTCHUNK(sl, c); ++c; ++sl; if (sl == 3) sl = 0; }
  VMW(0); BAR(); TESTCHUNK(sl, c);

  // ---- phase B: cold emit over hit chunks (wave-uniform mask, K from global)
  while (hitmask){
    int cc = __builtin_ctz(hitmask);
    hitmask &= hitmask - 1u;
    EMITCHUNK(cc);
  }
}

// ---------------- build per-head row lists + slot maps ----------------
__global__ void rowlist_k(const int* __restrict__ qflag, const int* __restrict__ kflag,
                          int* __restrict__ lcnt,
                          int* __restrict__ qlist, int* __restrict__ klist,
                          int* __restrict__ qslotm, int* __restrict__ kslotm){
  int side = blockIdx.y;
  int i = blockIdx.x*256 + threadIdx.x;
  const int* flag = side ? kflag : qflag;
  if (!flag[i]) return;
  int h = (i >> 11) & 15, b = i >> 15, row = i & 2047;
  int slot = atomicAdd(&lcnt[side*16 + h], 1);
  int* list = side ? klist : qlist;
  int* sm   = side ? kslotm : qslotm;
  if (slot < SLOTS){ list[h*SLOTS + slot] = (b << 11) | row; sm[i] = slot; }
  else sm[i] = -1;
}

// ---------------- exact fp32 rows, head-grouped, E-part-split ----------------
__global__ __launch_bounds__(256) void exact_rows_k(
    const float* __restrict__ x, const int* __restrict__ tmap,
    const float* __restrict__ Wq, const float* __restrict__ Wk,
    const float* __restrict__ Wv,
    const int* __restrict__ lcnt,
    const int* __restrict__ qlist, const int* __restrict__ klist,
    float* __restrict__ qex, float* __restrict__ kex, float* __restrict__ vex){
  int p = blockIdx.x, h = blockIdx.y, z = blockIdx.z;
  int R = lcnt[(z == 0 ? 0 : 16) + h]; if (R > SLOTS) R = SLOTS;
  if (R == 0) return;
  const float* W = (z == 0) ? Wq : (z == 1 ? Wk : Wv);
  const int* list = (z == 0) ? qlist : klist;
  float* dst = (z == 0) ? qex : (z == 1 ? kex : vex);
  int d = threadIdx.x >> 2, j = threadIdx.x & 3;
  const float4* w4 = reinterpret_cast<const float4*>(W + (size_t)(h*64 + d)*E_ + p*64 + j*16);
  float4 wa = w4[0], wb = w4[1], wcv = w4[2], wd = w4[3];
  for (int r = 0; r < R; ++r){
    int e = list[h*SLOTS + r];
    int b = e >> 11, rr = e & 2047;
    int row = (z == 0) ? rr : tmap[b*S_ + rr];
    const float4* x4 = reinterpret_cast<const float4*>(x + (size_t)(b*S_ + row)*E_ + p*64 + j*16);
    float acc = dot4(x4[0], wa) + dot4(x4[1], wb) + dot4(x4[2], wcv) + dot4(x4[3], wd);
    acc += __shfl_xor(acc, 1);
    acc += __shfl_xor(acc, 2);
    if (j == 0) atomicAdd(&dst[(size_t)(h*SLOTS + r)*64 + d], acc);
  }
}

// ---------------- exact d2 + survivor build ----------------
__global__ __launch_bounds__(256) void d2_survive_k(
    const unsigned* __restrict__ cnt, const unsigned* __restrict__ cand,
    const int* __restrict__ qslotm, const int* __restrict__ kslotm,
    const float* __restrict__ qex, const float* __restrict__ kex,
    unsigned* __restrict__ scnt, uint2* __restrict__ surv){
  unsigned n = *cnt; if (n > MAXCAND) n = MAXCAND;
  int wid = threadIdx.x >> 6, lane = threadIdx.x & 63;
  for (unsigned i = blockIdx.x*4 + wid; i < n; i += gridDim.x*4){
    unsigned u = cand[i];
    int b = (int)(u >> 26), h = (int)((u >> 22) & 15);
    int s = (int)((u >> 11) & 2047), tc = (int)(u & 2047);
    int qi = ((b*16 + h) << 11) | s, ki = ((b*16 + h) << 11) | tc;
    int qs = qslotm[qi], ks = kslotm[ki];
    float sq;
    if (qs >= 0 && ks >= 0){
      float a = qex[(size_t)(h*SLOTS + qs)*64 + lane] - kex[(size_t)(h*SLOTS + ks)*64 + lane];
      sq = a*a;
    } else sq = 1e30f;
    #pragma unroll
    for (int o = 32; o; o >>= 1) sq += __shfl_xor(sq, o);
    if (lane == 0 && sq < T_CUT){
      unsigned si = atomicAdd(scnt, 1u);
      if (si < MAXSURV){
        uint2 sv;
        sv.x = ((unsigned)b << 24) | ((unsigned)h << 20) | ((unsigned)s << 9) | (unsigned)ks;
        sv.y = __float_as_uint(expf(-sq));
        surv[si] = sv;
      }
    }
  }
}

// ---------------- scatter: out[b,s,:] += w * (v @ Wo^T) ----------------
__global__ __launch_bounds__(256) void scatter_k(
    const float* __restrict__ Wo, const float* __restrict__ vex,
    const unsigned* __restrict__ scnt, const uint2* __restrict__ surv,
    float* __restrict__ out){
  __shared__ float vsh[64];
  unsigned n = *scnt; if (n > MAXSURV) n = MAXSURV;
  unsigned items = n*4;
  for (unsigned it = blockIdx.x; it < items; it += gridDim.x){
    __syncthreads();
    uint2 sv = surv[it >> 2];
    int c = (int)(it & 3);
    int b = (int)(sv.x >> 24), h = (int)((sv.x >> 20) & 15);
    int s = (int)((sv.x >> 9) & 2047), ks = (int)(sv.x & 511);
    float w = __uint_as_float(sv.y);
    if (threadIdx.x < 64) vsh[threadIdx.x] = vex[(size_t)(h*SLOTS + ks)*64 + threadIdx.x];
    __syncthreads();
    int e = c*256 + threadIdx.x;
    const float4* wo4 = reinterpret_cast<const float4*>(Wo + (size_t)e*E_ + h*64);
    const float4* vv4 = reinterpret_cast<const float4*>(vsh);
    float a = 0.f;
    #pragma unroll
    for (int d2 = 0; d2 < 16; ++d2){
      float4 vv = vv4[d2], ww = wo4[d2];
      a += vv.x*ww.x + vv.y*ww.y + vv.z*ww.z + vv.w*ww.w;
    }
    atomicAdd(&out[(size_t)(b*S_ + s)*E_ + e], w*a);
  }
}

extern "C" void kernel_launch(void* const* d_in, const int* in_sizes, int n_in,
                              void* d_out, int out_size, void* d_ws, size_t ws_size,
                              hipStream_t stream){
  const float* x  = (const float*)d_in[0];
  const int* mask = (const int*)d_in[1];
  const float* Wq = (const float*)d_in[2];
  const float* Wk = (const float*)d_in[3];
  const float* Wv = (const float*)d_in[4];
  const float* Wo = (const float*)d_in[5];
  float* out = (float*)d_out;

  char* w = (char*)d_ws;
  unsigned short* Qhm = (unsigned short*)w; w += (size_t)BS_*E_*2;   // head-major [b,h][s][64]
  unsigned short* Kc  = (unsigned short*)w; w += (size_t)BS_*E_*2;   // head-major compacted K
  unsigned short* xb  = (unsigned short*)w; w += (size_t)BS_*E_*2;   // bf16 x, row-major
  unsigned short* Wqkb = (unsigned short*)w; w += (size_t)E_*E_*2*2; // Wq | Wk bf16
  float* qn  = (float*)w; w += (size_t)BHS_*4;
  float* knc = (float*)w; w += (size_t)BHS_*4;
  int* tmap   = (int*)w; w += (size_t)BS_*4;
  int* vcount = (int*)w; w += 256;
  unsigned* cand = (unsigned*)w; w += (size_t)MAXCAND*4;
  int* qslotm = (int*)w; w += (size_t)BHS_*4;
  int* kslotm = (int*)w; w += (size_t)BHS_*4;
  int* qlist  = (int*)w; w += (size_t)H_*SLOTS*4;
  int* klist  = (int*)w; w += (size_t)H_*SLOTS*4;
  uint2* surv = (uint2*)w; w += (size_t)MAXSURV*8;
  // ---- contiguous zeroed region (single memset): counters, flags, exact rows
  char* zbase = w;
  unsigned* cnt  = (unsigned*)w; w += 256;
  unsigned* scnt = (unsigned*)w; w += 256;
  int* lcnt = (int*)w; w += 256;
  int* qflag  = (int*)w; w += (size_t)BHS_*4;
  int* kflag  = (int*)w; w += (size_t)BHS_*4;
  float* qex = (float*)w; w += (size_t)H_*SLOTS*64*4;
  float* kex = (float*)w; w += (size_t)H_*SLOTS*64*4;
  float* vex = (float*)w; w += (size_t)H_*SLOTS*64*4;
  size_t zbytes = (size_t)(w - zbase);

  hipMemsetAsync(d_out, 0, (size_t)out_size*sizeof(float), stream);
  hipMemsetAsync(zbase, 0, zbytes, stream);

  // casts + mask compaction (one launch)
  cast_compact_k<<<5124, 256, 0, stream>>>(x, Wq, Wk, mask, xb, Wqkb, tmap, vcount);

  // fused Q|K projection, head-major out, norms in epilogue (one launch)
  proj_hm_k<<<dim3(64, 8, 2), 256, 0, stream>>>(xb, Wqkb, tmap, vcount, Qhm, Kc, qn, knc);

  // LDS-ring pair search (test-only hot loop + deferred emit)
  search_k<<<16*64, 256, 0, stream>>>(Qhm, Kc, qn, knc, vcount, cnt, cand, qflag, kflag);

  // sparse exact pipeline
  rowlist_k<<<dim3(BHS_/256, 2), 256, 0, stream>>>(qflag, kflag, lcnt, qlist, klist, qslotm, kslotm);
  exact_rows_k<<<dim3(16, 16, 3), 256, 0, stream>>>(x, tmap, Wq, Wk, Wv, lcnt, qlist, klist, qex, kex, vex);
  d2_survive_k<<<256, 256, 0, stream>>>(cnt, cand, qslotm, kslotm, qex, kex, scnt, surv);
  scatter_k<<<512, 256, 0, stream>>>(Wo, vex, scnt, surv, out);
}

// Round 12
// 168.182 us; speedup vs baseline: 1.7161x; 1.0400x over previous
//
#include <hip/hip_runtime.h>
#include <hip/hip_bf16.h>
#include <cstdint>
#include <cstddef>

#define B_ 4
#define S_ 2048
#define E_ 1024
#define H_ 16
#define BS_ (B_*S_)
#define BHS_ (B_*H_*S_)
#define MAXCAND (1u<<18)
#define MAXSURV 8192
#define SLOTS 512

static constexpr float T_SEARCH = 50.0f;  // bf16 search threshold (~8-sigma over cut)
static constexpr float T_CUT    = 48.5f;  // exact fp32 cut; e^-48.5 contribution ~300x under tol

typedef __attribute__((ext_vector_type(8))) short bf16x8;
typedef __attribute__((ext_vector_type(4))) float f32x4;

static __device__ __forceinline__ unsigned short f32_to_bf16(float f){
  unsigned u = __float_as_uint(f);
  return (unsigned short)((u + 0x7fffu + ((u >> 16) & 1u)) >> 16);  // RNE
}
static __device__ __forceinline__ void gload_lds16(const void* g, void* l){
  __builtin_amdgcn_global_load_lds(
      (const __attribute__((address_space(1))) unsigned int*)g,
      (__attribute__((address_space(3))) unsigned int*)l, 16, 0, 0);
}
static __device__ __forceinline__ float dot4(float4 a, float4 b){
  return a.x*b.x + a.y*b.y + a.z*b.z + a.w*b.w;
}

// ------- fused: f32->bf16 casts (x, Wq, Wk) + per-batch mask compaction -------
__global__ void cast_compact_k(const float* __restrict__ x,
                               const float* __restrict__ wq, const float* __restrict__ wk,
                               const int* __restrict__ mask,
                               unsigned short* __restrict__ xb, unsigned short* __restrict__ wqkb,
                               int* __restrict__ tmap, int* __restrict__ vcount){
  int blk = blockIdx.x;
  if (blk >= 5120){                     // mask compaction, b = blk-5120
    int b = blk - 5120, tid = threadIdx.x;
    __shared__ int ps[256];
    int loc[8]; int cnt = 0;
    #pragma unroll
    for (int j = 0; j < 8; ++j){ int m = mask[b*S_ + tid*8 + j]; loc[j] = m; cnt += m; }
    ps[tid] = cnt; __syncthreads();
    for (int off = 1; off < 256; off <<= 1){
      int v = (tid >= off) ? ps[tid-off] : 0;
      __syncthreads(); ps[tid] += v; __syncthreads();
    }
    int base = ps[tid] - cnt;
    #pragma unroll
    for (int j = 0; j < 8; ++j)
      if (loc[j]){ tmap[b*S_ + base] = tid*8 + j; ++base; }
    if (tid == 255) vcount[b] = ps[255];
    return;
  }
  const float* src; unsigned short* dst; int base;
  if (blk < 4096){ src = x;  dst = xb;                  base = blk; }
  else if (blk < 4608){ src = wq; dst = wqkb;           base = blk - 4096; }
  else { src = wk; dst = wqkb + (size_t)E_*E_;          base = blk - 4608; }
  size_t i = (size_t)base*256 + threadIdx.x;            // 8 elems per item
  const float4* s4 = reinterpret_cast<const float4*>(src) + 2*i;
  float4 a = s4[0], b = s4[1];
  float v[8] = {a.x,a.y,a.z,a.w,b.x,b.y,b.z,b.w};
  union { unsigned short us[8]; uint4 u4; } o;
  #pragma unroll
  for (int j = 0; j < 8; ++j) o.us[j] = f32_to_bf16(v[j]);
  reinterpret_cast<uint4*>(dst)[i] = o.u4;
}

// ------- fused Q|K projection, head-major out, norms in epilogue -------
__global__ __launch_bounds__(256) void proj_hm_k(
    const unsigned short* __restrict__ xb,
    const unsigned short* __restrict__ Wqkb,
    const int* __restrict__ tmap, const int* __restrict__ vcount,
    unsigned short* __restrict__ Qhm, unsigned short* __restrict__ Kc,
    float* __restrict__ qn, float* __restrict__ knc){
  const int z = blockIdx.z;
  const int m0 = blockIdx.x * 128, n0 = blockIdx.y * 128;
  const int bb = m0 >> 11, tc0 = m0 & 2047;
  const int vc = vcount[bb];
  if (z == 1 && tc0 >= vc) return;
  const unsigned short* Bw = Wqkb + (size_t)z*E_*E_;
  unsigned short* Out = z ? Kc : Qhm;
  float* Nrm = z ? knc : qn;

  __shared__ unsigned short At[128*64];
  __shared__ unsigned short Bt[128*64];
  const int tid = threadIdx.x, wave = tid >> 6, lane = tid & 63;
  const int wr = wave >> 1, wc = wave & 1;
  const int fr = lane & 15, fc = lane >> 4;
  const int srow = lane >> 3, sc = lane & 7;

  int arow[4];
  #pragma unroll
  for (int i = 0; i < 4; ++i){
    int r = wave*32 + i*8 + srow;
    int tc = tc0 + r;
    arow[i] = z ? ((tc < vc) ? tmap[bb*S_ + tc] : 0) : tc;
  }

  f32x4 acc[4][4] = {};

  for (int k0 = 0; k0 < 1024; k0 += 64){
    #pragma unroll
    for (int i = 0; i < 4; ++i){
      int r  = wave*32 + i*8 + srow;
      int cs = sc ^ (r & 7);
      gload_lds16(xb + ((size_t)(bb << 11) + arow[i])*1024 + k0 + cs*8, &At[(wave*32 + i*8)*64]);
      gload_lds16(Bw + (size_t)(n0 + r)*1024 + k0 + cs*8, &Bt[(wave*32 + i*8)*64]);
    }
    __syncthreads();
    #pragma unroll
    for (int kk = 0; kk < 2; ++kk){
      bf16x8 af[4], bf_[4];
      #pragma unroll
      for (int mf = 0; mf < 4; ++mf){
        int r = wr*64 + mf*16 + fr;
        af[mf] = *reinterpret_cast<const bf16x8*>(&At[r*64 + ((kk*4 + fc) ^ (r & 7))*8]);
      }
      #pragma unroll
      for (int nf = 0; nf < 4; ++nf){
        int r = wc*64 + nf*16 + fr;
        bf_[nf] = *reinterpret_cast<const bf16x8*>(&Bt[r*64 + ((kk*4 + fc) ^ (r & 7))*8]);
      }
      #pragma unroll
      for (int mf = 0; mf < 4; ++mf)
        #pragma unroll
        for (int nf = 0; nf < 4; ++nf)
          acc[mf][nf] = __builtin_amdgcn_mfma_f32_16x16x32_bf16(af[mf], bf_[nf], acc[mf][nf], 0, 0, 0);
    }
    __syncthreads();
  }

  const int h = (n0 >> 6) + wc;
  const size_t rowbase = (size_t)((bb << 4) | h)*S_;
  #pragma unroll
  for (int mf = 0; mf < 4; ++mf)
    #pragma unroll
    for (int r = 0; r < 4; ++r){
      int rowb = tc0 + wr*64 + mf*16 + fc*4 + r;
      #pragma unroll
      for (int nf = 0; nf < 4; ++nf)
        Out[(rowbase + rowb)*64 + nf*16 + fr] = f32_to_bf16(acc[mf][nf][r]);
      float s = 0.f;
      #pragma unroll
      for (int nf = 0; nf < 4; ++nf) s += acc[mf][nf][r]*acc[mf][nf][r];
      s += __shfl_xor(s, 1); s += __shfl_xor(s, 2);
      s += __shfl_xor(s, 4); s += __shfl_xor(s, 8);
      if (fr == 0) Nrm[rowbase + rowb] = s;
    }
}

// ------- LDS-ring candidate search: 64-row strips, test-only hot loop -------
#define VMW(N_) asm volatile("s_waitcnt vmcnt(" #N_ ")" ::: "memory")
#define BAR()  do{ __builtin_amdgcn_s_barrier(); __builtin_amdgcn_sched_barrier(0); }while(0)

#define STAGE_K(slot_, c_) do{                                                 \
  _Pragma("unroll") for (int j_ = 0; j_ < 2; ++j_){                            \
    int rr_ = wave*16 + j_*8 + srow;                                           \
    gload_lds16(Kh + (size_t)((c_)*64 + rr_)*64 + (sc ^ (rr_ & 7))*8,          \
                &Kt[slot_][(wave*16 + j_*8)*64]);                              \
  }                                                                            \
}while(0)

// phase A: 8 MFMA + 16 flat compares -> one hitmask bit. No index math/atomics.
#define TESTCHUNK(slot_, c_) do{                                               \
  int t0_ = (c_)*64;                                                           \
  bf16x8 af_[2], bfr_[4][2]; float knh_[4];                                    \
  { int r_ = wave*16 + fr;                                                     \
    _Pragma("unroll") for (int kk_ = 0; kk_ < 2; ++kk_)                        \
      af_[kk_] = *reinterpret_cast<const bf16x8*>(                             \
          &Qt[r_*64 + (((kk_*4 + fc) ^ (r_ & 7))*8)]); }                       \
  _Pragma("unroll") for (int nf_ = 0; nf_ < 4; ++nf_){                         \
    int tl_ = nf_*16 + fr;                                                     \
    _Pragma("unroll") for (int kk_ = 0; kk_ < 2; ++kk_)                        \
      bfr_[nf_][kk_] = *reinterpret_cast<const bf16x8*>(                       \
          &Kt[slot_][tl_*64 + (((kk_*4 + fc) ^ (tl_ & 7))*8)]);                \
    int t_ = t0_ + tl_;                                                        \
    knh_[nf_] = (t_ < vc) ? 0.5f*knl[t_] : 1e30f;                              \
  }                                                                            \
  f32x4 acc[4];                                                                \
  _Pragma("unroll") for (int nf_ = 0; nf_ < 4; ++nf_){                         \
    acc[nf_] = __builtin_amdgcn_mfma_f32_16x16x32_bf16(                        \
        af_[0], bfr_[nf_][0], z4, 0, 0, 0);                                    \
    acc[nf_] = __builtin_amdgcn_mfma_f32_16x16x32_bf16(                        \
        af_[1], bfr_[nf_][1], acc[nf_], 0, 0, 0);                              \
  }                                                                            \
  int hit_ = 0;                                                                \
  _Pragma("unroll") for (int nf_ = 0; nf_ < 4; ++nf_)                          \
  _Pragma("unroll") for (int r_ = 0; r_ < 4; ++r_)                             \
    hit_ |= (acc[nf_][r_] > qa[r_] + knh_[nf_]) ? 1 : 0;                       \
  if (__any(hit_)) hitmask |= (1u << (c_));                                    \
}while(0)

// phase B (cold): reload K chunk from global, redo MFMA, full emit scan.
#define EMITCHUNK(c_) do{                                                      \
  int t0_ = (c_)*64;                                                           \
  bf16x8 af_[2], bfr_[4][2]; float knh_[4];                                    \
  { int r_ = wave*16 + fr;                                                     \
    _Pragma("unroll") for (int kk_ = 0; kk_ < 2; ++kk_)                        \
      af_[kk_] = *reinterpret_cast<const bf16x8*>(                             \
          &Qt[r_*64 + (((kk_*4 + fc) ^ (r_ & 7))*8)]); }                       \
  _Pragma("unroll") for (int nf_ = 0; nf_ < 4; ++nf_){                         \
    int tl_ = nf_*16 + fr;                                                     \
    _Pragma("unroll") for (int kk_ = 0; kk_ < 2; ++kk_)                        \
      bfr_[nf_][kk_] = *reinterpret_cast<const bf16x8*>(                       \
          Kh + (size_t)(t0_ + tl_)*64 + (kk_*4 + fc)*8);                       \
    int t_ = t0_ + tl_;                                                        \
    knh_[nf_] = (t_ < vc) ? 0.5f*knl[t_] : 1e30f;                              \
  }                                                                            \
  f32x4 acc[4];                                                                \
  _Pragma("unroll") for (int nf_ = 0; nf_ < 4; ++nf_){                         \
    acc[nf_] = __builtin_amdgcn_mfma_f32_16x16x32_bf16(                        \
        af_[0], bfr_[nf_][0], z4, 0, 0, 0);                                    \
    acc[nf_] = __builtin_amdgcn_mfma_f32_16x16x32_bf16(                        \
        af_[1], bfr_[nf_][1], acc[nf_], 0, 0, 0);                              \
  }                                                                            \
  _Pragma("unroll") for (int nf_ = 0; nf_ < 4; ++nf_)                          \
  _Pragma("unroll") for (int r_ = 0; r_ < 4; ++r_){                            \
    if (acc[nf_][r_] > qa[r_] + knh_[nf_]){                                    \
      int t_ = t0_ + nf_*16 + fr;                                              \
      if (t_ < vc){                                                            \
        int s_ = s0 + wave*16 + fc*4 + r_;                                     \
        unsigned idx_ = atomicAdd(cnt, 1u);                                    \
        if (idx_ < MAXCAND)                                                    \
          cand[idx_] = ((unsigned)b << 26) | ((unsigned)h << 22)               \
                     | ((unsigned)s_ << 11) | (unsigned)t_;                    \
        qflag[(bh << 11) | s_] = 1;                                            \
        kflag[(bh << 11) | t_] = 1;                                            \
      }                                                                        \
    }                                                                          \
  }                                                                            \
}while(0)

__global__ __launch_bounds__(256) void search_k(
    const unsigned short* __restrict__ Qhm, const unsigned short* __restrict__ Kc,
    const float* __restrict__ qn, const float* __restrict__ knc,
    const int* __restrict__ vcount,
    unsigned* __restrict__ cnt, unsigned* __restrict__ cand,
    int* __restrict__ qflag, int* __restrict__ kflag){
  __shared__ unsigned short Qt[64*64];       // 8KB (64-row strip)
  __shared__ unsigned short Kt[3][64*64];    // 24KB ring
  __shared__ float knl[S_];                  // 8KB  -> 40KB total, 4 blocks/CU
  const int wave = threadIdx.x >> 6, lane = threadIdx.x & 63;
  const int bh = blockIdx.x & 63;
  const int s0 = (blockIdx.x >> 6) * 64;     // 32 strip-blocks
  const int b = bh >> 4, h = bh & 15;
  const int vc = vcount[b];
  const int nt = (vc + 63) >> 6;             // <= 32
  if (nt == 0) return;
  const int fr = lane & 15, fc = lane >> 4;
  const int srow = lane >> 3, sc = lane & 7;
  const unsigned short* Qh = Qhm + (size_t)bh*S_*64;
  const unsigned short* Kh = Kc + (size_t)bh*S_*64;
  const float* qnb = qn + (size_t)bh*S_;
  const float* knb = knc + (size_t)bh*S_;
  const f32x4 z4 = {0.f, 0.f, 0.f, 0.f};

  // qa thresholds: force-complete BEFORE staging so compiler VM loads don't
  // pollute the hand-counted vmcnt bookkeeping.
  float qa[4];
  #pragma unroll
  for (int r = 0; r < 4; ++r)
    qa[r] = 0.5f*(qnb[s0 + wave*16 + fc*4 + r] - T_SEARCH);
  float qamin = fminf(fminf(qa[0], qa[1]), fminf(qa[2], qa[3]));
  asm volatile("" :: "v"(qamin));
  asm volatile("s_waitcnt vmcnt(0)" ::: "memory");
  __builtin_amdgcn_sched_barrier(0);

  // ---- prologue staging: Q strip (2 ops) + kn row (2 ops) + K0,K1 (2 ops each)
  #pragma unroll
  for (int i = 0; i < 2; ++i){
    int r = wave*16 + i*8 + srow;
    gload_lds16(Qh + (size_t)(s0 + r)*64 + (sc ^ (r & 7))*8, &Qt[(wave*16 + i*8)*64]);
  }
  gload_lds16(knb + wave*512 + lane*4,       &knl[wave*512]);
  gload_lds16(knb + wave*512 + 256 + lane*4, &knl[wave*512 + 256]);
  STAGE_K(0, 0);
  if (nt > 1) STAGE_K(1, 1);

  unsigned hitmask = 0u;
  int c = 0, sl = 0;
  for (; c + 2 < nt; ++c){
    VMW(2); BAR();                       // own stage(c) retired; all waves synced
    int sl2 = sl + 2; if (sl2 >= 3) sl2 -= 3;
    STAGE_K(sl2, c + 2);                 // after barrier: ring-3 WAR-safe
    TESTCHUNK(sl, c);
    ++sl; if (sl == 3) sl = 0;
  }
  if (c + 1 < nt){ VMW(2); BAR(); TESTCHUNK(sl, c); ++c; ++sl; if (sl == 3) sl = 0; }
  VMW(0); BAR(); TESTCHUNK(sl, c);

  // ---- phase B: cold emit over hit chunks (wave-uniform mask, K from global)
  while (hitmask){
    int cc = __builtin_ctz(hitmask);
    hitmask &= hitmask - 1u;
    EMITCHUNK(cc);
  }
}

// ------- build per-head row lists + slot maps; zero allocated exact-rows -------
__global__ void rowlist_k(const int* __restrict__ qflag, const int* __restrict__ kflag,
                          int* __restrict__ lcnt,
                          int* __restrict__ qlist, int* __restrict__ klist,
                          int* __restrict__ qslotm, int* __restrict__ kslotm,
                          float* __restrict__ qex, float* __restrict__ kex,
                          float* __restrict__ vex){
  int side = blockIdx.y;
  int i = blockIdx.x*256 + threadIdx.x;
  const int* flag = side ? kflag : qflag;
  if (!flag[i]) return;
  int h = (i >> 11) & 15, b = i >> 15, row = i & 2047;
  int slot = atomicAdd(&lcnt[side*16 + h], 1);
  int* list = side ? klist : qlist;
  int* sm   = side ? kslotm : qslotm;
  if (slot < SLOTS){
    list[h*SLOTS + slot] = (b << 11) | row; sm[i] = slot;
    float4 z = {0.f,0.f,0.f,0.f};
    float4* d0 = reinterpret_cast<float4*>((side ? kex : qex) + (size_t)(h*SLOTS + slot)*64);
    #pragma unroll
    for (int j = 0; j < 16; ++j) d0[j] = z;
    if (side){
      float4* d1 = reinterpret_cast<float4*>(vex + (size_t)(h*SLOTS + slot)*64);
      #pragma unroll
      for (int j = 0; j < 16; ++j) d1[j] = z;
    }
  }
  else sm[i] = -1;
}

// ---------------- exact fp32 rows, head-grouped, E-part-split ----------------
__global__ __launch_bounds__(256) void exact_rows_k(
    const float* __restrict__ x, const int* __restrict__ tmap,
    const float* __restrict__ Wq, const float* __restrict__ Wk,
    const float* __restrict__ Wv,
    const int* __restrict__ lcnt,
    const int* __restrict__ qlist, const int* __restrict__ klist,
    float* __restrict__ qex, float* __restrict__ kex, float* __restrict__ vex){
  int p = blockIdx.x, h = blockIdx.y, z = blockIdx.z;
  int R = lcnt[(z == 0 ? 0 : 16) + h]; if (R > SLOTS) R = SLOTS;
  if (R == 0) return;
  const float* W = (z == 0) ? Wq : (z == 1 ? Wk : Wv);
  const int* list = (z == 0) ? qlist : klist;
  float* dst = (z == 0) ? qex : (z == 1 ? kex : vex);
  int d = threadIdx.x >> 2, j = threadIdx.x & 3;
  const float4* w4 = reinterpret_cast<const float4*>(W + (size_t)(h*64 + d)*E_ + p*64 + j*16);
  float4 wa = w4[0], wb = w4[1], wcv = w4[2], wd = w4[3];
  for (int r = 0; r < R; ++r){
    int e = list[h*SLOTS + r];
    int b = e >> 11, rr = e & 2047;
    int row = (z == 0) ? rr : tmap[b*S_ + rr];
    const float4* x4 = reinterpret_cast<const float4*>(x + (size_t)(b*S_ + row)*E_ + p*64 + j*16);
    float acc = dot4(x4[0], wa) + dot4(x4[1], wb) + dot4(x4[2], wcv) + dot4(x4[3], wd);
    acc += __shfl_xor(acc, 1);
    acc += __shfl_xor(acc, 2);
    if (j == 0) atomicAdd(&dst[(size_t)(h*SLOTS + r)*64 + d], acc);
  }
}

// ---------------- exact d2 + survivor build ----------------
__global__ __launch_bounds__(256) void d2_survive_k(
    const unsigned* __restrict__ cnt, const unsigned* __restrict__ cand,
    const int* __restrict__ qslotm, const int* __restrict__ kslotm,
    const float* __restrict__ qex, const float* __restrict__ kex,
    unsigned* __restrict__ scnt, uint2* __restrict__ surv){
  unsigned n = *cnt; if (n > MAXCAND) n = MAXCAND;
  int wid = threadIdx.x >> 6, lane = threadIdx.x & 63;
  for (unsigned i = blockIdx.x*4 + wid; i < n; i += gridDim.x*4){
    unsigned u = cand[i];
    int b = (int)(u >> 26), h = (int)((u >> 22) & 15);
    int s = (int)((u >> 11) & 2047), tc = (int)(u & 2047);
    int qi = ((b*16 + h) << 11) | s, ki = ((b*16 + h) << 11) | tc;
    int qs = qslotm[qi], ks = kslotm[ki];
    float sq;
    if (qs >= 0 && ks >= 0){
      float a = qex[(size_t)(h*SLOTS + qs)*64 + lane] - kex[(size_t)(h*SLOTS + ks)*64 + lane];
      sq = a*a;
    } else sq = 1e30f;
    #pragma unroll
    for (int o = 32; o; o >>= 1) sq += __shfl_xor(sq, o);
    if (lane == 0 && sq < T_CUT){
      unsigned si = atomicAdd(scnt, 1u);
      if (si < MAXSURV){
        uint2 sv;
        sv.x = ((unsigned)b << 24) | ((unsigned)h << 20) | ((unsigned)s << 9) | (unsigned)ks;
        sv.y = __float_as_uint(expf(-sq));
        surv[si] = sv;
      }
    }
  }
}

// ---------------- scatter: out[b,s,:] += w * (v @ Wo^T) ----------------
__global__ __launch_bounds__(256) void scatter_k(
    const float* __restrict__ Wo, const float* __restrict__ vex,
    const unsigned* __restrict__ scnt, const uint2* __restrict__ surv,
    float* __restrict__ out){
  __shared__ float vsh[64];
  unsigned n = *scnt; if (n > MAXSURV) n = MAXSURV;
  unsigned items = n*4;
  for (unsigned it = blockIdx.x; it < items; it += gridDim.x){
    __syncthreads();
    uint2 sv = surv[it >> 2];
    int c = (int)(it & 3);
    int b = (int)(sv.x >> 24), h = (int)((sv.x >> 20) & 15);
    int s = (int)((sv.x >> 9) & 2047), ks = (int)(sv.x & 511);
    float w = __uint_as_float(sv.y);
    if (threadIdx.x < 64) vsh[threadIdx.x] = vex[(size_t)(h*SLOTS + ks)*64 + threadIdx.x];
    __syncthreads();
    int e = c*256 + threadIdx.x;
    const float4* wo4 = reinterpret_cast<const float4*>(Wo + (size_t)e*E_ + h*64);
    const float4* vv4 = reinterpret_cast<const float4*>(vsh);
    float a = 0.f;
    #pragma unroll
    for (int d2 = 0; d2 < 16; ++d2){
      float4 vv = vv4[d2], ww = wo4[d2];
      a += vv.x*ww.x + vv.y*ww.y + vv.z*ww.z + vv.w*ww.w;
    }
    atomicAdd(&out[(size_t)(b*S_ + s)*E_ + e], w*a);
  }
}

extern "C" void kernel_launch(void* const* d_in, const int* in_sizes, int n_in,
                              void* d_out, int out_size, void* d_ws, size_t ws_size,
                              hipStream_t stream){
  const float* x  = (const float*)d_in[0];
  const int* mask = (const int*)d_in[1];
  const float* Wq = (const float*)d_in[2];
  const float* Wk = (const float*)d_in[3];
  const float* Wv = (const float*)d_in[4];
  const float* Wo = (const float*)d_in[5];
  float* out = (float*)d_out;

  char* w = (char*)d_ws;
  unsigned short* Qhm = (unsigned short*)w; w += (size_t)BS_*E_*2;   // head-major [b,h][s][64]
  unsigned short* Kc  = (unsigned short*)w; w += (size_t)BS_*E_*2;   // head-major compacted K
  unsigned short* xb  = (unsigned short*)w; w += (size_t)BS_*E_*2;   // bf16 x, row-major
  unsigned short* Wqkb = (unsigned short*)w; w += (size_t)E_*E_*2*2; // Wq | Wk bf16
  float* qn  = (float*)w; w += (size_t)BHS_*4;
  float* knc = (float*)w; w += (size_t)BHS_*4;
  int* tmap   = (int*)w; w += (size_t)BS_*4;
  int* vcount = (int*)w; w += 256;
  unsigned* cand = (unsigned*)w; w += (size_t)MAXCAND*4;
  int* qslotm = (int*)w; w += (size_t)BHS_*4;
  int* kslotm = (int*)w; w += (size_t)BHS_*4;
  int* qlist  = (int*)w; w += (size_t)H_*SLOTS*4;
  int* klist  = (int*)w; w += (size_t)H_*SLOTS*4;
  uint2* surv = (uint2*)w; w += (size_t)MAXSURV*8;
  float* qex = (float*)w; w += (size_t)H_*SLOTS*64*4;   // zeroed lazily by rowlist_k
  float* kex = (float*)w; w += (size_t)H_*SLOTS*64*4;
  float* vex = (float*)w; w += (size_t)H_*SLOTS*64*4;
  // ---- contiguous zeroed region (single small memset): counters + flags
  char* zbase = w;
  unsigned* cnt  = (unsigned*)w; w += 256;
  unsigned* scnt = (unsigned*)w; w += 256;
  int* lcnt = (int*)w; w += 256;
  int* qflag  = (int*)w; w += (size_t)BHS_*4;
  int* kflag  = (int*)w; w += (size_t)BHS_*4;
  size_t zbytes = (size_t)(w - zbase);

  hipMemsetAsync(d_out, 0, (size_t)out_size*sizeof(float), stream);
  hipMemsetAsync(zbase, 0, zbytes, stream);

  // casts + mask compaction (one launch)
  cast_compact_k<<<5124, 256, 0, stream>>>(x, Wq, Wk, mask, xb, Wqkb, tmap, vcount);

  // fused Q|K projection, head-major out, norms in epilogue (one launch)
  proj_hm_k<<<dim3(64, 8, 2), 256, 0, stream>>>(xb, Wqkb, tmap, vcount, Qhm, Kc, qn, knc);

  // LDS-ring pair search (64-row strips, test-only hot loop + deferred emit)
  search_k<<<32*64, 256, 0, stream>>>(Qhm, Kc, qn, knc, vcount, cnt, cand, qflag, kflag);

  // sparse exact pipeline (rowlist zeroes allocated qex/kex/vex rows)
  rowlist_k<<<dim3(BHS_/256, 2), 256, 0, stream>>>(qflag, kflag, lcnt, qlist, klist,
                                                   qslotm, kslotm, qex, kex, vex);
  exact_rows_k<<<dim3(16, 16, 3), 256, 0, stream>>>(x, tmap, Wq, Wk, Wv, lcnt, qlist, klist, qex, kex, vex);
  d2_survive_k<<<256, 256, 0, stream>>>(cnt, cand, qslotm, kslotm, qex, kex, scnt, surv);
  scatter_k<<<512, 256, 0, stream>>>(Wo, vex, scnt, surv, out);
}